// Round 1
// baseline (1248.722 us; speedup 1.0000x reference)
//
#include <hip/hip_runtime.h>

namespace {

constexpr int kNodes = 4000;
constexpr int kRels  = 400;
constexpr int kB     = 32;
constexpr int kV     = 20;
constexpr int kN     = 32000;
constexpr int kE     = 256000;
constexpr int kH     = 128;
constexpr int kL     = 3;
constexpr int kMPad  = 4096;        // alpha_w m-dim padded to 32*128
constexpr int kBV    = kB * kV;     // 640

typedef __attribute__((ext_vector_type(8))) short bf16x8;
typedef __attribute__((ext_vector_type(4))) float f32x4;

__device__ inline unsigned short f2bf(float f){
  unsigned int u = __float_as_uint(f);
  u += 0x7FFFu + ((u >> 16) & 1u);      // round-to-nearest-even
  return (unsigned short)(u >> 16);
}

// ---------- prep kernels ----------

// transpose lin_w (m=0) and nn_w[0..2] (m=1..3), 128x128 each
__global__ void transpose_kernel(const float* __restrict__ lin_w, const float* __restrict__ nn_w,
                                 float* __restrict__ lin_wT, float* __restrict__ nn_wT){
  int m = blockIdx.x;
  const float* in = (m == 0) ? lin_w : nn_w + (size_t)(m-1)*kH*kH;
  float* out      = (m == 0) ? lin_wT : nn_wT + (size_t)(m-1)*kH*kH;
  for (int i = threadIdx.x; i < kH*kH; i += blockDim.x){
    int r = i >> 7, c = i & (kH-1);
    out[c*kH + r] = in[i];
  }
}

// rows 0..3999 -> emb_lin = node_emb@lin_w.T + b ; rows 4000..4399 -> rel_lin
__global__ __launch_bounds__(128) void proj_kernel(const float* __restrict__ node_emb,
    const float* __restrict__ rel_emb, const float* __restrict__ lin_wT,
    const float* __restrict__ lin_b, float* __restrict__ emb_lin, float* __restrict__ rel_lin){
  int row = blockIdx.x;
  const float* src; float* dst;
  if (row < kNodes){ src = node_emb + (size_t)row*kH; dst = emb_lin + (size_t)row*kH; }
  else             { src = rel_emb + (size_t)(row-kNodes)*kH; dst = rel_lin + (size_t)(row-kNodes)*kH; }
  __shared__ float rs[kH];
  int h = threadIdx.x;
  rs[h] = src[h];
  __syncthreads();
  float acc = lin_b[h];
#pragma unroll 8
  for (int k = 0; k < kH; k++) acc = fmaf(rs[k], lin_wT[k*kH + h], acc);
  dst[h] = acc;
}

__global__ void gather_x0_kernel(const int* __restrict__ node_ids,
                                 const float* __restrict__ emb_lin, float* __restrict__ x){
  int idx = blockIdx.x*256 + threadIdx.x;
  if (idx < kN*kH){
    int i = idx >> 7, c = idx & (kH-1);
    x[idx] = emb_lin[(size_t)node_ids[i]*kH + c];
  }
}

// relterm[l][r][c] = (rel_lin[r]·wr_w[l] + wr_b[l]) * rel_lin[r][c]
__global__ __launch_bounds__(128) void relterm_kernel(const float* __restrict__ rel_lin,
    const float* __restrict__ wr_w, const float* __restrict__ wr_b, float* __restrict__ relterm){
  int l = blockIdx.x / kRels, r = blockIdx.x % kRels;
  int t = threadIdx.x;
  float rl = rel_lin[(size_t)r*kH + t];
  __shared__ float red[kH];
  red[t] = rl * wr_w[l*kH + t];
  __syncthreads();
  for (int o = 64; o > 0; o >>= 1){
    if (t < o) red[t] += red[t+o];
    __syncthreads();
  }
  float w = red[0] + wr_b[l];
  relterm[((size_t)l*kRels + r)*kH + t] = w * rl;
}

__global__ void hist_kernel(const int* __restrict__ keys, int n, int* __restrict__ bins){
  int i = blockIdx.x*256 + threadIdx.x;
  if (i < n) atomicAdd(&bins[keys[i]], 1);
}

__global__ __launch_bounds__(1024) void scan_kernel(const int* __restrict__ deg, int n,
                                                    int* __restrict__ starts, int* __restrict__ cursor){
  __shared__ int buf[1024];
  __shared__ int carry;
  int t = threadIdx.x;
  if (t == 0) carry = 0;
  __syncthreads();
  for (int base = 0; base < n; base += 1024){
    int v = (base + t < n) ? deg[base + t] : 0;
    buf[t] = v;
    __syncthreads();
    for (int o = 1; o < 1024; o <<= 1){
      int add = (t >= o) ? buf[t-o] : 0;
      __syncthreads();
      buf[t] += add;
      __syncthreads();
    }
    int exc = buf[t] - v + carry;
    if (base + t < n){ starts[base+t] = exc; cursor[base+t] = exc; }
    __syncthreads();
    if (t == 1023) carry += buf[1023];
    __syncthreads();
  }
  if (t == 0) starts[n] = carry;
}

__global__ void scatter_kernel(const int* __restrict__ dst, int n,
                               int* __restrict__ cursor, int* __restrict__ perm){
  int e = blockIdx.x*256 + threadIdx.x;
  if (e < n){
    int p = atomicAdd(&cursor[dst[e]], 1);
    perm[p] = e;
  }
}

// ---------- attention path ----------

__global__ void cvt_visit_kernel(const float* __restrict__ visit, unsigned short* __restrict__ out){
  int i = blockIdx.x*256 + threadIdx.x;     // vec8 index, total 640*4000/8
  if (i >= kBV*kNodes/8) return;
  const float4 a = *reinterpret_cast<const float4*>(visit + (size_t)i*8);
  const float4 b = *reinterpret_cast<const float4*>(visit + (size_t)i*8 + 4);
  unsigned short r[8] = {f2bf(a.x),f2bf(a.y),f2bf(a.z),f2bf(a.w),
                         f2bf(b.x),f2bf(b.y),f2bf(b.z),f2bf(b.w)};
  *reinterpret_cast<uint4*>(out + (size_t)i*8) = *reinterpret_cast<uint4*>(r);
}

// alpha_w[l] (4000x4000 f32) -> (4096x4000 bf16), pad rows zeroed
__global__ void cvtW_kernel(const float* __restrict__ W, unsigned short* __restrict__ out){
  int i = blockIdx.x*256 + threadIdx.x;     // vec8 index over 4096*500
  if (i >= kMPad*(kNodes/8)) return;
  int row = i / (kNodes/8);
  int col = (i - row*(kNodes/8)) * 8;
  unsigned short r[8];
  if (row < kNodes){
    const float* p = W + (size_t)row*kNodes + col;
    const float4 a = *reinterpret_cast<const float4*>(p);
    const float4 b = *reinterpret_cast<const float4*>(p + 4);
    r[0]=f2bf(a.x); r[1]=f2bf(a.y); r[2]=f2bf(a.z); r[3]=f2bf(a.w);
    r[4]=f2bf(b.x); r[5]=f2bf(b.y); r[6]=f2bf(b.z); r[7]=f2bf(b.w);
  } else {
    for (int q = 0; q < 8; q++) r[q] = 0;
  }
  *reinterpret_cast<uint4*>(out + (size_t)row*kNodes + col) = *reinterpret_cast<uint4*>(r);
}

// C(640 x 4096) = A(640 x 4000) @ B(4096 x 4000)^T, bf16 in / f32 out
__global__ __launch_bounds__(256) void gemm_bt_bf16(const unsigned short* __restrict__ A,
    const unsigned short* __restrict__ B, float* __restrict__ C, int K){
  __shared__ unsigned short As[128*32];
  __shared__ unsigned short Bs[128*32];
  int bm = blockIdx.x, bn = blockIdx.y;
  int t = threadIdx.x;
  int lane = t & 63, wave = t >> 6;
  int wm = (wave >> 1) * 64, wn = (wave & 1) * 64;
  int r = lane & 15, g = lane >> 4;

  int srow = t >> 1;
  int sk   = (t & 1) * 16;
  const unsigned short* Ag = A + (size_t)(bm*128 + srow)*K + sk;
  const unsigned short* Bg = B + (size_t)(bn*128 + srow)*K + sk;
  unsigned short* Asw = &As[srow*32 + sk];
  unsigned short* Bsw = &Bs[srow*32 + sk];

  f32x4 acc[4][4];
#pragma unroll
  for (int i = 0; i < 4; i++)
#pragma unroll
    for (int j = 0; j < 4; j++) acc[i][j] = f32x4{0.f,0.f,0.f,0.f};

  for (int k0 = 0; k0 < K; k0 += 32){
    uint4 a0 = *reinterpret_cast<const uint4*>(Ag + k0);
    uint4 a1 = *reinterpret_cast<const uint4*>(Ag + k0 + 8);
    uint4 b0 = *reinterpret_cast<const uint4*>(Bg + k0);
    uint4 b1 = *reinterpret_cast<const uint4*>(Bg + k0 + 8);
    __syncthreads();
    *reinterpret_cast<uint4*>(Asw)     = a0;
    *reinterpret_cast<uint4*>(Asw + 8) = a1;
    *reinterpret_cast<uint4*>(Bsw)     = b0;
    *reinterpret_cast<uint4*>(Bsw + 8) = b1;
    __syncthreads();
    bf16x8 af[4], bf[4];
#pragma unroll
    for (int i = 0; i < 4; i++){
      af[i] = *reinterpret_cast<const bf16x8*>(&As[(wm + i*16 + r)*32 + g*8]);
      bf[i] = *reinterpret_cast<const bf16x8*>(&Bs[(wn + i*16 + r)*32 + g*8]);
    }
#pragma unroll
    for (int i = 0; i < 4; i++)
#pragma unroll
      for (int j = 0; j < 4; j++)
        acc[i][j] = __builtin_amdgcn_mfma_f32_16x16x32_bf16(af[i], bf[j], acc[i][j], 0, 0, 0);
  }
#pragma unroll
  for (int i = 0; i < 4; i++)
#pragma unroll
    for (int j = 0; j < 4; j++){
      int row = bm*128 + wm + i*16 + g*4;
      int col = bn*128 + wn + j*16 + r;
#pragma unroll
      for (int q = 0; q < 4; q++)
        C[(size_t)(row + q)*kMPad + col] = acc[i][j][q];
    }
}

// beta[bv] = tanh(visit[bv]·beta_w_l + beta_b[l]) * exp(0.03*(V - v))
__global__ __launch_bounds__(256) void beta_kernel(const float* __restrict__ visit,
    const float* __restrict__ beta_w_l, const float* __restrict__ beta_b, int l,
    float* __restrict__ beta){
  int wid = (blockIdx.x*256 + threadIdx.x) >> 6;
  int lane = threadIdx.x & 63;
  if (wid >= kBV) return;
  const float* row = visit + (size_t)wid*kNodes;
  float s = 0.f;
  for (int k = lane; k < kNodes; k += 64) s = fmaf(row[k], beta_w_l[k], s);
#pragma unroll
  for (int o = 32; o > 0; o >>= 1) s += __shfl_down(s, o);
  if (lane == 0){
    int v = wid % kV;
    float lam = __expf(0.03f * (float)(kV - v));
    beta[wid] = tanhf(s + beta_b[l]) * lam;
  }
}

// attn[b][m] = sum_v softmax_v(S[b,:,m]) * beta[b,v]
__global__ __launch_bounds__(256) void attn_kernel(const float* __restrict__ S,
    const float* __restrict__ beta, float* __restrict__ attn){
  int idx = blockIdx.x*256 + threadIdx.x;
  if (idx >= kB*kNodes) return;
  int b = idx / kNodes;
  int m = idx - b*kNodes;
  const float* Sp = S + (size_t)b*kV*kMPad + m;
  float vals[kV];
  float mx = -1e30f;
#pragma unroll
  for (int v = 0; v < kV; v++){ float s = Sp[(size_t)v*kMPad]; vals[v] = s; mx = fmaxf(mx, s); }
  float se = 0.f, ws = 0.f;
  const float* bp = beta + b*kV;
#pragma unroll
  for (int v = 0; v < kV; v++){ float e = __expf(vals[v] - mx); se += e; ws = fmaf(e, bp[v], ws); }
  attn[idx] = ws / se;
}

// ---------- GNN layer ----------

// one wave per node: agg[n][:] = sum_{e: dst=n} relu(x[src]*attn[b_src,nid_src] + relterm[rel])
__global__ __launch_bounds__(256) void agg_kernel(const int* __restrict__ starts,
    const int* __restrict__ perm, const int* __restrict__ src, const int* __restrict__ rel_ids,
    const int* __restrict__ batch, const int* __restrict__ node_ids,
    const float* __restrict__ attn_l, const float* __restrict__ relterm_l,
    const float* __restrict__ x, float* __restrict__ agg){
  int wid = (blockIdx.x*256 + threadIdx.x) >> 6;
  int lane = threadIdx.x & 63;
  if (wid >= kN) return;
  int p0 = starts[wid], p1 = starts[wid+1];
  int c = lane*2;
  float a0 = 0.f, a1 = 0.f;
  for (int p = p0; p < p1; p++){
    int e = perm[p];
    int s = src[e];
    float at = attn_l[batch[s]*kNodes + node_ids[s]];
    float2 xv = *reinterpret_cast<const float2*>(&x[(size_t)s*kH + c]);
    float2 rt = *reinterpret_cast<const float2*>(&relterm_l[(size_t)rel_ids[e]*kH + c]);
    float m0 = fmaf(xv.x, at, rt.x); m0 = m0 > 0.f ? m0 : 0.f;
    float m1 = fmaf(xv.y, at, rt.y); m1 = m1 > 0.f ? m1 : 0.f;
    a0 += m0; a1 += m1;
  }
  *reinterpret_cast<float2*>(&agg[(size_t)wid*kH + c]) = float2{a0, a1};
}

// x[i] = relu((agg[i]+x[i]) @ nn_w.T + nn_b)   (in-place, row-local)
__global__ __launch_bounds__(256) void nn_kernel(const float* __restrict__ agg,
    float* __restrict__ x, const float* __restrict__ nn_wT_l, const float* __restrict__ nn_b_l){
  __shared__ float rows[8][kH];
  int rb = blockIdx.x * 8;
  int t = threadIdx.x;
#pragma unroll
  for (int i = 0; i < 4; i++){
    int idx = t + i*256;
    int rr = idx >> 7, cc = idx & (kH-1);
    size_t gi = (size_t)(rb + rr)*kH + cc;
    rows[rr][cc] = agg[gi] + x[gi];
  }
  __syncthreads();
  int cc = t & (kH-1);
  int r0 = (t >> 7) * 4;
  float acc0 = 0.f, acc1 = 0.f, acc2 = 0.f, acc3 = 0.f;
#pragma unroll 8
  for (int k = 0; k < kH; k++){
    float w = nn_wT_l[k*kH + cc];
    acc0 = fmaf(rows[r0+0][k], w, acc0);
    acc1 = fmaf(rows[r0+1][k], w, acc1);
    acc2 = fmaf(rows[r0+2][k], w, acc2);
    acc3 = fmaf(rows[r0+3][k], w, acc3);
  }
  float b = nn_b_l[cc];
  x[(size_t)(rb+r0+0)*kH + cc] = fmaxf(acc0 + b, 0.f);
  x[(size_t)(rb+r0+1)*kH + cc] = fmaxf(acc1 + b, 0.f);
  x[(size_t)(rb+r0+2)*kH + cc] = fmaxf(acc2 + b, 0.f);
  x[(size_t)(rb+r0+3)*kH + cc] = fmaxf(acc3 + b, 0.f);
}

// ---------- readout ----------

__global__ __launch_bounds__(128) void pool_kernel(const float* __restrict__ x,
    const int* __restrict__ batch, float* __restrict__ xg_sum){
  int i0 = blockIdx.x * 128;
  int c = threadIdx.x;
  float acc = 0.f;
  int cur = batch[i0];
  for (int i = i0; i < i0 + 128; i++){
    int b = batch[i];
    if (b != cur){ atomicAdd(&xg_sum[cur*kH + c], acc); acc = 0.f; cur = b; }
    acc += x[(size_t)i*kH + c];
  }
  atomicAdd(&xg_sum[cur*kH + c], acc);
}

__global__ __launch_bounds__(128) void xnode1_kernel(const float* __restrict__ ehr,
    const float* __restrict__ node_emb, float* __restrict__ tbuf){
  int b = blockIdx.x, c = threadIdx.x;
  float acc = 0.f, s = 0.f;
  for (int n = 0; n < kNodes; n++){
    float e = ehr[(size_t)b*kNodes + n];
    s += e;
    acc = fmaf(e, node_emb[(size_t)n*kH + c], acc);
  }
  tbuf[b*kH + c] = acc / s;
}

__global__ __launch_bounds__(128) void xnode2_kernel(const float* __restrict__ tbuf,
    const float* __restrict__ lin_wT, const float* __restrict__ lin_b, float* __restrict__ xn){
  int b = blockIdx.x, h = threadIdx.x;
  __shared__ float ts[kH];
  ts[h] = tbuf[b*kH + h];
  __syncthreads();
  float acc = lin_b[h];
#pragma unroll 8
  for (int k = 0; k < kH; k++) acc = fmaf(ts[k], lin_wT[k*kH + h], acc);
  xn[b*kH + h] = acc;
}

__global__ __launch_bounds__(128) void final_kernel(const float* __restrict__ xg_sum,
    const int* __restrict__ cnt, const float* __restrict__ xn,
    const float* __restrict__ mlp_w, const float* __restrict__ mlp_b, float* __restrict__ out){
  int b = blockIdx.x, o = threadIdx.x;
  __shared__ float v[2*kH];
  int c = cnt[b]; if (c < 1) c = 1;
  float inv = 1.f / (float)c;
  v[o]      = xg_sum[b*kH + o] * inv;
  v[kH + o] = xn[b*kH + o];
  __syncthreads();
  float acc = mlp_b[o];
#pragma unroll 8
  for (int k = 0; k < 2*kH; k++) acc = fmaf(v[k], mlp_w[(size_t)o*2*kH + k], acc);
  out[b*kH + o] = acc;
}

} // namespace

extern "C" void kernel_launch(void* const* d_in, const int* in_sizes, int n_in,
                              void* d_out, int out_size, void* d_ws, size_t ws_size,
                              hipStream_t stream){
  const int*   node_ids = (const int*)d_in[0];
  const int*   rel_ids  = (const int*)d_in[1];
  const int*   e_src    = (const int*)d_in[2];
  const int*   e_dst    = e_src + kE;
  const int*   batch    = (const int*)d_in[3];
  const float* visit    = (const float*)d_in[4];
  const float* ehr      = (const float*)d_in[5];
  const float* node_emb = (const float*)d_in[6];
  const float* rel_emb  = (const float*)d_in[7];
  const float* lin_w    = (const float*)d_in[8];
  const float* lin_b    = (const float*)d_in[9];
  const float* alpha_w  = (const float*)d_in[10];
  const float* beta_w   = (const float*)d_in[12];
  const float* beta_b   = (const float*)d_in[13];
  const float* wr_w     = (const float*)d_in[14];
  const float* wr_b     = (const float*)d_in[15];
  const float* nn_w     = (const float*)d_in[16];
  const float* nn_b     = (const float*)d_in[17];
  const float* mlp_w    = (const float*)d_in[18];
  const float* mlp_b    = (const float*)d_in[19];
  float* out = (float*)d_out;

  char* w = (char*)d_ws;
  auto alloc = [&](size_t bytes)->char*{
    char* p = w; w += (bytes + 255) & ~(size_t)255; return p;
  };
  // zero-region (memset each launch)
  int*   deg    = (int*)  alloc((size_t)kN*4);
  int*   cnt    = (int*)  alloc(kB*4);
  float* xgsum  = (float*)alloc((size_t)kB*kH*4);
  size_t zero_bytes = (size_t)(w - (char*)d_ws);
  // rest
  int*   starts = (int*)  alloc((size_t)(kN+1)*4);
  int*   cursor = (int*)  alloc((size_t)kN*4);
  int*   perm   = (int*)  alloc((size_t)kE*4);
  float* embLin = (float*)alloc((size_t)kNodes*kH*4);
  float* relLin = (float*)alloc((size_t)kRels*kH*4);
  float* relterm= (float*)alloc((size_t)kL*kRels*kH*4);
  float* linwT  = (float*)alloc((size_t)kH*kH*4);
  float* nnwT   = (float*)alloc((size_t)kL*kH*kH*4);
  float* x      = (float*)alloc((size_t)kN*kH*4);
  float* agg    = (float*)alloc((size_t)kN*kH*4);
  unsigned short* visitbf = (unsigned short*)alloc((size_t)kBV*kNodes*2);
  unsigned short* awbf    = (unsigned short*)alloc((size_t)kMPad*kNodes*2);
  float* S      = (float*)alloc((size_t)kBV*kMPad*4);
  float* attn   = (float*)alloc((size_t)kL*kB*kNodes*4);
  float* beta   = (float*)alloc((size_t)kBV*4);
  float* tbuf   = (float*)alloc((size_t)kB*kH*4);
  float* xn     = (float*)alloc((size_t)kB*kH*4);
  if ((size_t)(w - (char*)d_ws) > ws_size) return;   // ws too small: fail visibly

  hipMemsetAsync(d_ws, 0, zero_bytes, stream);

  transpose_kernel<<<4, 256, 0, stream>>>(lin_w, nn_w, linwT, nnwT);
  proj_kernel<<<kNodes + kRels, 128, 0, stream>>>(node_emb, rel_emb, linwT, lin_b, embLin, relLin);
  gather_x0_kernel<<<(kN*kH)/256, 256, 0, stream>>>(node_ids, embLin, x);
  relterm_kernel<<<kL*kRels, 128, 0, stream>>>(relLin, wr_w, wr_b, relterm);

  hist_kernel<<<(kE+255)/256, 256, 0, stream>>>(e_dst, kE, deg);
  hist_kernel<<<(kN+255)/256, 256, 0, stream>>>(batch, kN, cnt);
  scan_kernel<<<1, 1024, 0, stream>>>(deg, kN, starts, cursor);
  scatter_kernel<<<(kE+255)/256, 256, 0, stream>>>(e_dst, kE, cursor, perm);

  cvt_visit_kernel<<<(kBV*kNodes/8 + 255)/256, 256, 0, stream>>>(visit, visitbf);

  for (int l = 0; l < kL; l++){
    cvtW_kernel<<<(kMPad*(kNodes/8) + 255)/256, 256, 0, stream>>>(
        alpha_w + (size_t)l*kNodes*kNodes, awbf);
    gemm_bt_bf16<<<dim3(kBV/128, kMPad/128), 256, 0, stream>>>(visitbf, awbf, S, kNodes);
    beta_kernel<<<kBV/4, 256, 0, stream>>>(visit, beta_w + (size_t)l*kNodes, beta_b, l, beta);
    attn_kernel<<<(kB*kNodes + 255)/256, 256, 0, stream>>>(S, beta, attn + (size_t)l*kB*kNodes);
  }

  for (int l = 0; l < kL; l++){
    agg_kernel<<<kN/4, 256, 0, stream>>>(starts, perm, e_src, rel_ids, batch, node_ids,
        attn + (size_t)l*kB*kNodes, relterm + (size_t)l*kRels*kH, x, agg);
    nn_kernel<<<kN/8, 256, 0, stream>>>(agg, x, nnwT + (size_t)l*kH*kH, nn_b + (size_t)l*kH);
  }

  pool_kernel<<<kN/128, 128, 0, stream>>>(x, batch, xgsum);
  xnode1_kernel<<<kB, 128, 0, stream>>>(ehr, node_emb, tbuf);
  xnode2_kernel<<<kB, 128, 0, stream>>>(tbuf, linwT, lin_b, xn);
  final_kernel<<<kB, 128, 0, stream>>>(xgsum, cnt, xn, mlp_w, mlp_b, out);
}

// Round 3
// 720.475 us; speedup vs baseline: 1.7332x; 1.7332x over previous
//
#include <hip/hip_runtime.h>

namespace {

constexpr int kNodes = 4000;        // node-TYPE vocabulary (attn/alpha space)
constexpr int kRels  = 400;
constexpr int kB     = 32;
constexpr int kV     = 20;
constexpr int kN     = 32000;       // graph nodes (CSR space)
constexpr int kE     = 256000;
constexpr int kH     = 128;
constexpr int kL     = 3;
constexpr int kMPad  = 4096;        // alpha_w m-dim padded to 32*128
constexpr int kBV    = kB * kV;     // 640
constexpr int kNB    = 32;          // CSR sort blocks
constexpr int kChunk = kE / kNB;    // 8000 edges per sort block
constexpr int kHalf  = 16000;       // bins per LDS pass (64KB LDS); 2*kHalf == kN

typedef __attribute__((ext_vector_type(8))) short bf16x8;
typedef __attribute__((ext_vector_type(4))) float f32x4;

__device__ inline unsigned short f2bf(float f){
  unsigned int u = __float_as_uint(f);
  u += 0x7FFFu + ((u >> 16) & 1u);      // round-to-nearest-even
  return (unsigned short)(u >> 16);
}

// ---------- prep kernels ----------

__global__ void transpose_kernel(const float* __restrict__ lin_w, const float* __restrict__ nn_w,
                                 float* __restrict__ lin_wT, float* __restrict__ nn_wT){
  int m = blockIdx.x;
  const float* in = (m == 0) ? lin_w : nn_w + (size_t)(m-1)*kH*kH;
  float* out      = (m == 0) ? lin_wT : nn_wT + (size_t)(m-1)*kH*kH;
  for (int i = threadIdx.x; i < kH*kH; i += blockDim.x){
    int r = i >> 7, c = i & (kH-1);
    out[c*kH + r] = in[i];
  }
}

__global__ __launch_bounds__(128) void proj_kernel(const float* __restrict__ node_emb,
    const float* __restrict__ rel_emb, const float* __restrict__ lin_wT,
    const float* __restrict__ lin_b, float* __restrict__ emb_lin, float* __restrict__ rel_lin){
  int row = blockIdx.x;
  const float* src; float* dst;
  if (row < kNodes){ src = node_emb + (size_t)row*kH; dst = emb_lin + (size_t)row*kH; }
  else             { src = rel_emb + (size_t)(row-kNodes)*kH; dst = rel_lin + (size_t)(row-kNodes)*kH; }
  __shared__ float rs[kH];
  int h = threadIdx.x;
  rs[h] = src[h];
  __syncthreads();
  float acc = lin_b[h];
#pragma unroll 8
  for (int k = 0; k < kH; k++) acc = fmaf(rs[k], lin_wT[k*kH + h], acc);
  dst[h] = acc;
}

__global__ void gather_x0_kernel(const int* __restrict__ node_ids,
                                 const float* __restrict__ emb_lin, float* __restrict__ x){
  int idx = blockIdx.x*256 + threadIdx.x;
  if (idx < kN*kH){
    int i = idx >> 7, c = idx & (kH-1);
    x[idx] = emb_lin[(size_t)node_ids[i]*kH + c];
  }
}

__global__ __launch_bounds__(128) void relterm_kernel(const float* __restrict__ rel_lin,
    const float* __restrict__ wr_w, const float* __restrict__ wr_b, float* __restrict__ relterm){
  int l = blockIdx.x / kRels, r = blockIdx.x % kRels;
  int t = threadIdx.x;
  float rl = rel_lin[(size_t)r*kH + t];
  __shared__ float red[kH];
  red[t] = rl * wr_w[l*kH + t];
  __syncthreads();
  for (int o = 64; o > 0; o >>= 1){
    if (t < o) red[t] += red[t+o];
    __syncthreads();
  }
  float w = red[0] + wr_b[l];
  relterm[((size_t)l*kRels + r)*kH + t] = w * rl;
}

// ---------- CSR build over kN graph nodes (no global atomics) ----------

// per-block LDS histogram over one bin-half; records per-edge rank within (block, bin)
__global__ __launch_bounds__(256) void csr_hist_kernel(const int* __restrict__ dst,
    unsigned short* __restrict__ rank, unsigned int* __restrict__ hpart){
  __shared__ unsigned int hb[kHalf];
  int p = blockIdx.x;
  int base = blockIdx.y * kHalf;
  int t = threadIdx.x;
  for (int i = t; i < kHalf; i += 256) hb[i] = 0u;
  __syncthreads();
  for (int i = t; i < kChunk; i += 256){
    int e = p*kChunk + i;
    int d = dst[e];
    int rel = d - base;
    if ((unsigned)rel < (unsigned)kHalf){
      rank[e] = (unsigned short)atomicAdd(&hb[rel], 1u);
    }
  }
  __syncthreads();
  for (int i = t; i < kHalf; i += 256)
    hpart[(size_t)p*kN + base + i] = hb[i];
}

// per-bin: exclusive scan over blocks, IN PLACE in hpart; total -> deg
__global__ __launch_bounds__(256) void csr_col_kernel(unsigned int* __restrict__ hpart,
    int* __restrict__ deg){
  int bin = blockIdx.x*256 + threadIdx.x;
  if (bin >= kN) return;
  unsigned int s = 0;
#pragma unroll
  for (int p = 0; p < kNB; p++){
    size_t idx = (size_t)p*kN + bin;
    unsigned int v = hpart[idx];
    hpart[idx] = s;
    s += v;
  }
  deg[bin] = (int)s;
}

// hierarchical exclusive scan of deg[kN] -> starts
__global__ __launch_bounds__(256) void scanA_kernel(const int* __restrict__ deg,
    int* __restrict__ starts, int* __restrict__ bsum){
  __shared__ int buf[256];
  int gid = blockIdx.x*256 + threadIdx.x;
  int t = threadIdx.x;
  int v = (gid < kN) ? deg[gid] : 0;
  buf[t] = v;
  __syncthreads();
  for (int o = 1; o < 256; o <<= 1){
    int add = (t >= o) ? buf[t-o] : 0;
    __syncthreads();
    buf[t] += add;
    __syncthreads();
  }
  if (gid < kN) starts[gid] = buf[t] - v;
  if (t == 255) bsum[blockIdx.x] = buf[255];
}

__global__ __launch_bounds__(128) void scanB_kernel(const int* __restrict__ bsum,
    int* __restrict__ boffs, int nblk){
  __shared__ int buf[128];
  int t = threadIdx.x;
  int v = (t < nblk) ? bsum[t] : 0;
  buf[t] = v;
  __syncthreads();
  for (int o = 1; o < 128; o <<= 1){
    int add = (t >= o) ? buf[t-o] : 0;
    __syncthreads();
    buf[t] += add;
    __syncthreads();
  }
  if (t < nblk) boffs[t] = buf[t] - v;
}

__global__ __launch_bounds__(256) void scanC_kernel(int* __restrict__ starts,
    const int* __restrict__ boffs){
  int gid = blockIdx.x*256 + threadIdx.x;
  if (gid < kN) starts[gid] += boffs[blockIdx.x];
  if (gid == kN-1) starts[kN] = kE;
}

__global__ __launch_bounds__(256) void csr_place_kernel(const int* __restrict__ dst,
    const int* __restrict__ starts, const unsigned int* __restrict__ colOff,
    const unsigned short* __restrict__ rank, int* __restrict__ perm){
  int blk = blockIdx.x;                 // 128 blocks x 2000 edges
  int p = blk >> 2;                     // 4 blocks per sort chunk
  for (int i = threadIdx.x; i < 2000; i += 256){
    int e = blk*2000 + i;
    int d = dst[e];
    int pos = starts[d] + (int)colOff[(size_t)p*kN + d] + (int)rank[e];
    perm[pos] = e;
  }
}

// batch boundaries via binary search (batch is sorted)
__global__ void ub_kernel(const int* __restrict__ batch, int* __restrict__ ub){
  int j = threadIdx.x;
  if (j > kB) return;
  int lo = 0, hi = kN;
  while (lo < hi){
    int mid = (lo + hi) >> 1;
    if (batch[mid] < j) lo = mid + 1; else hi = mid;
  }
  ub[j] = lo;
}

// ---------- attention path ----------

__global__ void cvt_visit_kernel(const float* __restrict__ visit, unsigned short* __restrict__ out){
  int i = blockIdx.x*256 + threadIdx.x;
  if (i >= kBV*kNodes/8) return;
  const float4 a = *reinterpret_cast<const float4*>(visit + (size_t)i*8);
  const float4 b = *reinterpret_cast<const float4*>(visit + (size_t)i*8 + 4);
  unsigned short r[8] = {f2bf(a.x),f2bf(a.y),f2bf(a.z),f2bf(a.w),
                         f2bf(b.x),f2bf(b.y),f2bf(b.z),f2bf(b.w)};
  *reinterpret_cast<uint4*>(out + (size_t)i*8) = *reinterpret_cast<uint4*>(r);
}

__global__ void cvtW_kernel(const float* __restrict__ W, unsigned short* __restrict__ out){
  int i = blockIdx.x*256 + threadIdx.x;
  if (i >= kMPad*(kNodes/8)) return;
  int row = i / (kNodes/8);
  int col = (i - row*(kNodes/8)) * 8;
  unsigned short r[8];
  if (row < kNodes){
    const float* p = W + (size_t)row*kNodes + col;
    const float4 a = *reinterpret_cast<const float4*>(p);
    const float4 b = *reinterpret_cast<const float4*>(p + 4);
    r[0]=f2bf(a.x); r[1]=f2bf(a.y); r[2]=f2bf(a.z); r[3]=f2bf(a.w);
    r[4]=f2bf(b.x); r[5]=f2bf(b.y); r[6]=f2bf(b.z); r[7]=f2bf(b.w);
  } else {
    for (int q = 0; q < 8; q++) r[q] = 0;
  }
  *reinterpret_cast<uint4*>(out + (size_t)row*kNodes + col) = *reinterpret_cast<uint4*>(r);
}

// C(640 x 4096) = A(640 x K) @ B(4096 x K)^T, split-K over blockIdx.z
__global__ __launch_bounds__(256) void gemm_bt_bf16(const unsigned short* __restrict__ A,
    const unsigned short* __restrict__ B, float* __restrict__ Cbase){
  __shared__ unsigned short As[128*32];
  __shared__ unsigned short Bs[128*32];
  int bm = blockIdx.x, bn = blockIdx.y, z = blockIdx.z;
  int kBeg = z ? 2016 : 0;
  int kEnd = z ? kNodes : 2016;
  float* C = Cbase + (size_t)z * kBV * kMPad;
  int t = threadIdx.x;
  int lane = t & 63, wave = t >> 6;
  int wm = (wave >> 1) * 64, wn = (wave & 1) * 64;
  int r = lane & 15, g = lane >> 4;

  int srow = t >> 1;
  int sk   = (t & 1) * 16;
  const unsigned short* Ag = A + (size_t)(bm*128 + srow)*kNodes + sk;
  const unsigned short* Bg = B + (size_t)(bn*128 + srow)*kNodes + sk;
  unsigned short* Asw = &As[srow*32 + sk];
  unsigned short* Bsw = &Bs[srow*32 + sk];

  f32x4 acc[4][4];
#pragma unroll
  for (int i = 0; i < 4; i++)
#pragma unroll
    for (int j = 0; j < 4; j++) acc[i][j] = f32x4{0.f,0.f,0.f,0.f};

  for (int k0 = kBeg; k0 < kEnd; k0 += 32){
    uint4 a0 = *reinterpret_cast<const uint4*>(Ag + k0);
    uint4 a1 = *reinterpret_cast<const uint4*>(Ag + k0 + 8);
    uint4 b0 = *reinterpret_cast<const uint4*>(Bg + k0);
    uint4 b1 = *reinterpret_cast<const uint4*>(Bg + k0 + 8);
    __syncthreads();
    *reinterpret_cast<uint4*>(Asw)     = a0;
    *reinterpret_cast<uint4*>(Asw + 8) = a1;
    *reinterpret_cast<uint4*>(Bsw)     = b0;
    *reinterpret_cast<uint4*>(Bsw + 8) = b1;
    __syncthreads();
    bf16x8 af[4], bf[4];
#pragma unroll
    for (int i = 0; i < 4; i++){
      af[i] = *reinterpret_cast<const bf16x8*>(&As[(wm + i*16 + r)*32 + g*8]);
      bf[i] = *reinterpret_cast<const bf16x8*>(&Bs[(wn + i*16 + r)*32 + g*8]);
    }
#pragma unroll
    for (int i = 0; i < 4; i++)
#pragma unroll
      for (int j = 0; j < 4; j++)
        acc[i][j] = __builtin_amdgcn_mfma_f32_16x16x32_bf16(af[i], bf[j], acc[i][j], 0, 0, 0);
  }
#pragma unroll
  for (int i = 0; i < 4; i++)
#pragma unroll
    for (int j = 0; j < 4; j++){
      int row = bm*128 + wm + i*16 + g*4;
      int col = bn*128 + wn + j*16 + r;
#pragma unroll
      for (int q = 0; q < 4; q++)
        C[(size_t)(row + q)*kMPad + col] = acc[i][j][q];
    }
}

// beta[l][bv] = tanh(visit[bv]·beta_w[l] + beta_b[l]) * exp(0.03*(V - v)), all layers
__global__ __launch_bounds__(256) void beta_all_kernel(const float* __restrict__ visit,
    const float* __restrict__ beta_w, const float* __restrict__ beta_b,
    float* __restrict__ beta){
  int wid = (blockIdx.x*256 + threadIdx.x) >> 6;
  int lane = threadIdx.x & 63;
  if (wid >= kL*kBV) return;
  int l = wid / kBV, bv = wid - l*kBV;
  const float* row = visit + (size_t)bv*kNodes;
  const float* bw = beta_w + (size_t)l*kNodes;
  float s = 0.f;
  for (int k = lane; k < kNodes; k += 64) s = fmaf(row[k], bw[k], s);
#pragma unroll
  for (int o = 32; o > 0; o >>= 1) s += __shfl_down(s, o);
  if (lane == 0){
    int v = bv % kV;
    float lam = __expf(0.03f * (float)(kV - v));
    beta[wid] = tanhf(s + beta_b[l]) * lam;
  }
}

// attn[b][m] = sum_v softmax_v(S0+S1) * beta[b,v]
__global__ __launch_bounds__(256) void attn_kernel(const float* __restrict__ S,
    const float* __restrict__ beta_l, float* __restrict__ attn){
  int idx = blockIdx.x*256 + threadIdx.x;
  if (idx >= kB*kNodes) return;
  int b = idx / kNodes;
  int m = idx - b*kNodes;
  const float* S0 = S + (size_t)b*kV*kMPad + m;
  const float* S1 = S0 + (size_t)kBV*kMPad;
  float vals[kV];
  float mx = -1e30f;
#pragma unroll
  for (int v = 0; v < kV; v++){
    float s = S0[(size_t)v*kMPad] + S1[(size_t)v*kMPad];
    vals[v] = s; mx = fmaxf(mx, s);
  }
  float se = 0.f, ws = 0.f;
  const float* bp = beta_l + b*kV;
#pragma unroll
  for (int v = 0; v < kV; v++){ float e = __expf(vals[v] - mx); se += e; ws = fmaf(e, bp[v], ws); }
  attn[idx] = ws / se;
}

// ---------- GNN layer ----------

__global__ __launch_bounds__(256) void agg_kernel(const int* __restrict__ starts,
    const int* __restrict__ perm, const int* __restrict__ src, const int* __restrict__ rel_ids,
    const int* __restrict__ batch, const int* __restrict__ node_ids,
    const float* __restrict__ attn_l, const float* __restrict__ relterm_l,
    const float* __restrict__ x, float* __restrict__ agg){
  int wid = (blockIdx.x*256 + threadIdx.x) >> 6;
  int lane = threadIdx.x & 63;
  if (wid >= kN) return;
  int p0 = starts[wid], p1 = starts[wid+1];
  int c = lane*2;
  float a0 = 0.f, a1 = 0.f;
  for (int p = p0; p < p1; p++){
    int e = perm[p];
    int s = src[e];
    float at = attn_l[batch[s]*kNodes + node_ids[s]];
    float2 xv = *reinterpret_cast<const float2*>(&x[(size_t)s*kH + c]);
    float2 rt = *reinterpret_cast<const float2*>(&relterm_l[(size_t)rel_ids[e]*kH + c]);
    float m0 = fmaf(xv.x, at, rt.x); m0 = m0 > 0.f ? m0 : 0.f;
    float m1 = fmaf(xv.y, at, rt.y); m1 = m1 > 0.f ? m1 : 0.f;
    a0 += m0; a1 += m1;
  }
  *reinterpret_cast<float2*>(&agg[(size_t)wid*kH + c]) = float2{a0, a1};
}

__global__ __launch_bounds__(256) void nn_kernel(const float* __restrict__ agg,
    float* __restrict__ x, const float* __restrict__ nn_wT_l, const float* __restrict__ nn_b_l){
  __shared__ float rows[8][kH];
  int rb = blockIdx.x * 8;
  int t = threadIdx.x;
#pragma unroll
  for (int i = 0; i < 4; i++){
    int idx = t + i*256;
    int rr = idx >> 7, cc = idx & (kH-1);
    size_t gi = (size_t)(rb + rr)*kH + cc;
    rows[rr][cc] = agg[gi] + x[gi];
  }
  __syncthreads();
  int cc = t & (kH-1);
  int r0 = (t >> 7) * 4;
  float acc0 = 0.f, acc1 = 0.f, acc2 = 0.f, acc3 = 0.f;
#pragma unroll 8
  for (int k = 0; k < kH; k++){
    float w = nn_wT_l[k*kH + cc];
    acc0 = fmaf(rows[r0+0][k], w, acc0);
    acc1 = fmaf(rows[r0+1][k], w, acc1);
    acc2 = fmaf(rows[r0+2][k], w, acc2);
    acc3 = fmaf(rows[r0+3][k], w, acc3);
  }
  float b = nn_b_l[cc];
  x[(size_t)(rb+r0+0)*kH + cc] = fmaxf(acc0 + b, 0.f);
  x[(size_t)(rb+r0+1)*kH + cc] = fmaxf(acc1 + b, 0.f);
  x[(size_t)(rb+r0+2)*kH + cc] = fmaxf(acc2 + b, 0.f);
  x[(size_t)(rb+r0+3)*kH + cc] = fmaxf(acc3 + b, 0.f);
}

// ---------- readout (no atomics) ----------

__global__ __launch_bounds__(128) void pool_part_kernel(const float* __restrict__ x,
    const int* __restrict__ ub, float* __restrict__ pp){
  int s = blockIdx.x, b = blockIdx.y, c = threadIdx.x;
  int lo = ub[b], len = ub[b+1] - lo;
  int i0 = lo + (int)(((long long)len * s) >> 3);
  int i1 = lo + (int)(((long long)len * (s+1)) >> 3);
  float acc = 0.f;
  for (int i = i0; i < i1; i++) acc += x[(size_t)i*kH + c];
  pp[(size_t)(b*8 + s)*kH + c] = acc;
}

__global__ __launch_bounds__(128) void pool_fin_kernel(const float* __restrict__ pp,
    const int* __restrict__ ub, float* __restrict__ xg){
  int b = blockIdx.x, c = threadIdx.x;
  float s = 0.f;
#pragma unroll
  for (int q = 0; q < 8; q++) s += pp[(size_t)(b*8 + q)*kH + c];
  int len = ub[b+1] - ub[b]; if (len < 1) len = 1;
  xg[b*kH + c] = s / (float)len;
}

__global__ __launch_bounds__(128) void xnode1_kernel(const float* __restrict__ ehr,
    const float* __restrict__ node_emb, float* __restrict__ pn, float* __restrict__ ps){
  int s = blockIdx.x, b = blockIdx.y, c = threadIdx.x;
  int n0 = s * (kNodes/8), n1 = n0 + (kNodes/8);
  float acc = 0.f, es = 0.f;
  for (int n = n0; n < n1; n++){
    float e = ehr[(size_t)b*kNodes + n];
    es += e;
    acc = fmaf(e, node_emb[(size_t)n*kH + c], acc);
  }
  pn[(size_t)(b*8 + s)*kH + c] = acc;
  if (c == 0) ps[b*8 + s] = es;
}

__global__ __launch_bounds__(128) void xnode2_kernel(const float* __restrict__ pn,
    const float* __restrict__ ps, const float* __restrict__ lin_wT,
    const float* __restrict__ lin_b, float* __restrict__ xn){
  int b = blockIdx.x, h = threadIdx.x;
  __shared__ float ts[kH];
  float acc = 0.f, es = 0.f;
#pragma unroll
  for (int q = 0; q < 8; q++){
    acc += pn[(size_t)(b*8 + q)*kH + h];
    es  += ps[b*8 + q];
  }
  ts[h] = acc / es;
  __syncthreads();
  float r = lin_b[h];
#pragma unroll 8
  for (int k = 0; k < kH; k++) r = fmaf(ts[k], lin_wT[k*kH + h], r);
  xn[b*kH + h] = r;
}

__global__ __launch_bounds__(128) void final_kernel(const float* __restrict__ xg,
    const float* __restrict__ xn, const float* __restrict__ mlp_w,
    const float* __restrict__ mlp_b, float* __restrict__ out){
  int b = blockIdx.x, o = threadIdx.x;
  __shared__ float v[2*kH];
  v[o]      = xg[b*kH + o];
  v[kH + o] = xn[b*kH + o];
  __syncthreads();
  float acc = mlp_b[o];
#pragma unroll 8
  for (int k = 0; k < 2*kH; k++) acc = fmaf(v[k], mlp_w[(size_t)o*2*kH + k], acc);
  out[b*kH + o] = acc;
}

} // namespace

extern "C" void kernel_launch(void* const* d_in, const int* in_sizes, int n_in,
                              void* d_out, int out_size, void* d_ws, size_t ws_size,
                              hipStream_t stream){
  const int*   node_ids = (const int*)d_in[0];
  const int*   rel_ids  = (const int*)d_in[1];
  const int*   e_src    = (const int*)d_in[2];
  const int*   e_dst    = e_src + kE;
  const int*   batch    = (const int*)d_in[3];
  const float* visit    = (const float*)d_in[4];
  const float* ehr      = (const float*)d_in[5];
  const float* node_emb = (const float*)d_in[6];
  const float* rel_emb  = (const float*)d_in[7];
  const float* lin_w    = (const float*)d_in[8];
  const float* lin_b    = (const float*)d_in[9];
  const float* alpha_w  = (const float*)d_in[10];
  const float* beta_w   = (const float*)d_in[12];
  const float* beta_b   = (const float*)d_in[13];
  const float* wr_w     = (const float*)d_in[14];
  const float* wr_b     = (const float*)d_in[15];
  const float* nn_w     = (const float*)d_in[16];
  const float* nn_b     = (const float*)d_in[17];
  const float* mlp_w    = (const float*)d_in[18];
  const float* mlp_b    = (const float*)d_in[19];
  float* out = (float*)d_out;

  char* w = (char*)d_ws;
  auto alloc = [&](size_t bytes)->char*{
    char* p = w; w += (bytes + 255) & ~(size_t)255; return p;
  };
  int*   starts = (int*)  alloc((size_t)(kN+1)*4);
  int*   deg    = (int*)  alloc((size_t)kN*4);
  int*   bsum   = (int*)  alloc(256*4);
  int*   boffs  = (int*)  alloc(256*4);
  int*   ub     = (int*)  alloc((kB+1)*4);
  int*   perm   = (int*)  alloc((size_t)kE*4);
  unsigned short* rank = (unsigned short*)alloc((size_t)kE*2);
  unsigned int* hpart  = (unsigned int*)alloc((size_t)kNB*kN*4);   // becomes colOff in place
  float* embLin = (float*)alloc((size_t)kNodes*kH*4);
  float* relLin = (float*)alloc((size_t)kRels*kH*4);
  float* relterm= (float*)alloc((size_t)kL*kRels*kH*4);
  float* linwT  = (float*)alloc((size_t)kH*kH*4);
  float* nnwT   = (float*)alloc((size_t)kL*kH*kH*4);
  float* x      = (float*)alloc((size_t)kN*kH*4);
  float* agg    = (float*)alloc((size_t)kN*kH*4);
  unsigned short* visitbf = (unsigned short*)alloc((size_t)kBV*kNodes*2);
  unsigned short* awbf    = (unsigned short*)alloc((size_t)kMPad*kNodes*2);
  float* S      = (float*)alloc((size_t)2*kBV*kMPad*4);
  float* attn   = (float*)alloc((size_t)kL*kB*kNodes*4);
  float* beta   = (float*)alloc((size_t)kL*kBV*4);
  float* pp     = (float*)alloc((size_t)kB*8*kH*4);
  float* xg     = (float*)alloc((size_t)kB*kH*4);
  float* pn     = (float*)alloc((size_t)kB*8*kH*4);
  float* ps     = (float*)alloc((size_t)kB*8*4);
  float* xn     = (float*)alloc((size_t)kB*kH*4);
  if ((size_t)(w - (char*)d_ws) > ws_size) return;   // ws too small: fail visibly

  // prep
  transpose_kernel<<<4, 256, 0, stream>>>(lin_w, nn_w, linwT, nnwT);
  proj_kernel<<<kNodes + kRels, 128, 0, stream>>>(node_emb, rel_emb, linwT, lin_b, embLin, relLin);
  gather_x0_kernel<<<(kN*kH)/256, 256, 0, stream>>>(node_ids, embLin, x);
  relterm_kernel<<<kL*kRels, 128, 0, stream>>>(relLin, wr_w, wr_b, relterm);

  // CSR build (no global atomics)
  csr_hist_kernel<<<dim3(kNB, 2), 256, 0, stream>>>(e_dst, rank, hpart);
  csr_col_kernel<<<(kN+255)/256, 256, 0, stream>>>(hpart, deg);
  scanA_kernel<<<(kN+255)/256, 256, 0, stream>>>(deg, starts, bsum);
  scanB_kernel<<<1, 128, 0, stream>>>(bsum, boffs, (kN+255)/256);
  scanC_kernel<<<(kN+255)/256, 256, 0, stream>>>(starts, boffs);
  csr_place_kernel<<<128, 256, 0, stream>>>(e_dst, starts, hpart, rank, perm);
  ub_kernel<<<1, 64, 0, stream>>>(batch, ub);

  // attention path
  cvt_visit_kernel<<<(kBV*kNodes/8 + 255)/256, 256, 0, stream>>>(visit, visitbf);
  beta_all_kernel<<<kL*kBV/4, 256, 0, stream>>>(visit, beta_w, beta_b, beta);

  for (int l = 0; l < kL; l++){
    cvtW_kernel<<<(kMPad*(kNodes/8) + 255)/256, 256, 0, stream>>>(
        alpha_w + (size_t)l*kNodes*kNodes, awbf);
    gemm_bt_bf16<<<dim3(kBV/128, kMPad/128, 2), 256, 0, stream>>>(visitbf, awbf, S);
    attn_kernel<<<(kB*kNodes + 255)/256, 256, 0, stream>>>(S, beta + (size_t)l*kBV,
        attn + (size_t)l*kB*kNodes);
  }

  // GNN layers
  for (int l = 0; l < kL; l++){
    agg_kernel<<<kN/4, 256, 0, stream>>>(starts, perm, e_src, rel_ids, batch, node_ids,
        attn + (size_t)l*kB*kNodes, relterm + (size_t)l*kRels*kH, x, agg);
    nn_kernel<<<kN/8, 256, 0, stream>>>(agg, x, nnwT + (size_t)l*kH*kH, nn_b + (size_t)l*kH);
  }

  // readout
  pool_part_kernel<<<dim3(8, kB), 128, 0, stream>>>(x, ub, pp);
  pool_fin_kernel<<<kB, 128, 0, stream>>>(pp, ub, xg);
  xnode1_kernel<<<dim3(8, kB), 128, 0, stream>>>(ehr, node_emb, pn, ps);
  xnode2_kernel<<<kB, 128, 0, stream>>>(pn, ps, linwT, lin_b, xn);
  final_kernel<<<kB, 128, 0, stream>>>(xg, xn, mlp_w, mlp_b, out);
}

// Round 5
// 632.861 us; speedup vs baseline: 1.9731x; 1.1384x over previous
//
#include <hip/hip_runtime.h>

namespace {

constexpr int kNodes = 4000;        // node-TYPE vocabulary (attn/alpha space)
constexpr int kRels  = 400;
constexpr int kB     = 32;
constexpr int kV     = 20;
constexpr int kN     = 32000;       // graph nodes (CSR space)
constexpr int kE     = 256000;
constexpr int kH     = 128;
constexpr int kL     = 3;
constexpr int kMPad  = 4096;        // alpha_w m-dim padded to 32*128
constexpr int kBV    = kB * kV;     // 640
constexpr int kNB    = 32;          // CSR sort blocks
constexpr int kChunk = kE / kNB;    // 8000 edges per sort block
constexpr int kHalf  = 16000;       // bins per LDS pass (64KB LDS); 2*kHalf == kN

typedef __attribute__((ext_vector_type(8))) short bf16x8;
typedef __attribute__((ext_vector_type(4))) float f32x4;

__device__ inline unsigned short f2bf(float f){
  unsigned int u = __float_as_uint(f);
  u += 0x7FFFu + ((u >> 16) & 1u);      // round-to-nearest-even
  return (unsigned short)(u >> 16);
}

// global->LDS direct copy, 16B per lane, dest = wave-uniform base + lane*16
__device__ inline void gload_lds16(const unsigned short* g, unsigned short* l){
  __builtin_amdgcn_global_load_lds(
      (const __attribute__((address_space(1))) unsigned int*)(g),
      (__attribute__((address_space(3))) unsigned int*)(l),
      16, 0, 0);
}

// ---------- prep kernels ----------

__global__ void transpose_kernel(const float* __restrict__ lin_w, const float* __restrict__ nn_w,
                                 float* __restrict__ lin_wT, float* __restrict__ nn_wT){
  int m = blockIdx.x;
  const float* in = (m == 0) ? lin_w : nn_w + (size_t)(m-1)*kH*kH;
  float* out      = (m == 0) ? lin_wT : nn_wT + (size_t)(m-1)*kH*kH;
  for (int i = threadIdx.x; i < kH*kH; i += blockDim.x){
    int r = i >> 7, c = i & (kH-1);
    out[c*kH + r] = in[i];
  }
}

__global__ __launch_bounds__(128) void proj_kernel(const float* __restrict__ node_emb,
    const float* __restrict__ rel_emb, const float* __restrict__ lin_wT,
    const float* __restrict__ lin_b, float* __restrict__ emb_lin, float* __restrict__ rel_lin){
  int row = blockIdx.x;
  const float* src; float* dst;
  if (row < kNodes){ src = node_emb + (size_t)row*kH; dst = emb_lin + (size_t)row*kH; }
  else             { src = rel_emb + (size_t)(row-kNodes)*kH; dst = rel_lin + (size_t)(row-kNodes)*kH; }
  __shared__ float rs[kH];
  int h = threadIdx.x;
  rs[h] = src[h];
  __syncthreads();
  float acc = lin_b[h];
#pragma unroll 8
  for (int k = 0; k < kH; k++) acc = fmaf(rs[k], lin_wT[k*kH + h], acc);
  dst[h] = acc;
}

__global__ void gather_x0_kernel(const int* __restrict__ node_ids,
                                 const float* __restrict__ emb_lin, float* __restrict__ x){
  int idx = blockIdx.x*256 + threadIdx.x;
  if (idx < kN*kH){
    int i = idx >> 7, c = idx & (kH-1);
    x[idx] = emb_lin[(size_t)node_ids[i]*kH + c];
  }
}

__global__ __launch_bounds__(128) void relterm_kernel(const float* __restrict__ rel_lin,
    const float* __restrict__ wr_w, const float* __restrict__ wr_b, float* __restrict__ relterm){
  int l = blockIdx.x / kRels, r = blockIdx.x % kRels;
  int t = threadIdx.x;
  float rl = rel_lin[(size_t)r*kH + t];
  __shared__ float red[kH];
  red[t] = rl * wr_w[l*kH + t];
  __syncthreads();
  for (int o = 64; o > 0; o >>= 1){
    if (t < o) red[t] += red[t+o];
    __syncthreads();
  }
  float w = red[0] + wr_b[l];
  relterm[((size_t)l*kRels + r)*kH + t] = w * rl;
}

// ---------- CSR build over kN graph nodes (no global atomics) ----------

__global__ __launch_bounds__(256) void csr_hist_kernel(const int* __restrict__ dst,
    unsigned short* __restrict__ rank, unsigned int* __restrict__ hpart){
  __shared__ unsigned int hb[kHalf];
  int p = blockIdx.x;
  int base = blockIdx.y * kHalf;
  int t = threadIdx.x;
  for (int i = t; i < kHalf; i += 256) hb[i] = 0u;
  __syncthreads();
  for (int i = t; i < kChunk; i += 256){
    int e = p*kChunk + i;
    int d = dst[e];
    int rel = d - base;
    if ((unsigned)rel < (unsigned)kHalf){
      rank[e] = (unsigned short)atomicAdd(&hb[rel], 1u);
    }
  }
  __syncthreads();
  for (int i = t; i < kHalf; i += 256)
    hpart[(size_t)p*kN + base + i] = hb[i];
}

__global__ __launch_bounds__(256) void csr_col_kernel(unsigned int* __restrict__ hpart,
    int* __restrict__ deg){
  int bin = blockIdx.x*256 + threadIdx.x;
  if (bin >= kN) return;
  unsigned int s = 0;
#pragma unroll
  for (int p = 0; p < kNB; p++){
    size_t idx = (size_t)p*kN + bin;
    unsigned int v = hpart[idx];
    hpart[idx] = s;
    s += v;
  }
  deg[bin] = (int)s;
}

__global__ __launch_bounds__(256) void scanA_kernel(const int* __restrict__ deg,
    int* __restrict__ starts, int* __restrict__ bsum){
  __shared__ int buf[256];
  int gid = blockIdx.x*256 + threadIdx.x;
  int t = threadIdx.x;
  int v = (gid < kN) ? deg[gid] : 0;
  buf[t] = v;
  __syncthreads();
  for (int o = 1; o < 256; o <<= 1){
    int add = (t >= o) ? buf[t-o] : 0;
    __syncthreads();
    buf[t] += add;
    __syncthreads();
  }
  if (gid < kN) starts[gid] = buf[t] - v;
  if (t == 255) bsum[blockIdx.x] = buf[255];
}

__global__ __launch_bounds__(128) void scanB_kernel(const int* __restrict__ bsum,
    int* __restrict__ boffs, int nblk){
  __shared__ int buf[128];
  int t = threadIdx.x;
  int v = (t < nblk) ? bsum[t] : 0;
  buf[t] = v;
  __syncthreads();
  for (int o = 1; o < 128; o <<= 1){
    int add = (t >= o) ? buf[t-o] : 0;
    __syncthreads();
    buf[t] += add;
    __syncthreads();
  }
  if (t < nblk) boffs[t] = buf[t] - v;
}

__global__ __launch_bounds__(256) void scanC_kernel(int* __restrict__ starts,
    const int* __restrict__ boffs){
  int gid = blockIdx.x*256 + threadIdx.x;
  if (gid < kN) starts[gid] += boffs[blockIdx.x];
  if (gid == kN-1) starts[kN] = kE;
}

__global__ __launch_bounds__(256) void csr_place_kernel(const int* __restrict__ dst,
    const int* __restrict__ starts, const unsigned int* __restrict__ colOff,
    const unsigned short* __restrict__ rank, int* __restrict__ perm){
  int blk = blockIdx.x;                 // 128 blocks x 2000 edges
  int p = blk >> 2;                     // 4 blocks per sort chunk
  for (int i = threadIdx.x; i < 2000; i += 256){
    int e = blk*2000 + i;
    int d = dst[e];
    int pos = starts[d] + (int)colOff[(size_t)p*kN + d] + (int)rank[e];
    perm[pos] = e;
  }
}

__global__ void ub_kernel(const int* __restrict__ batch, int* __restrict__ ub){
  int j = threadIdx.x;
  if (j > kB) return;
  int lo = 0, hi = kN;
  while (lo < hi){
    int mid = (lo + hi) >> 1;
    if (batch[mid] < j) lo = mid + 1; else hi = mid;
  }
  ub[j] = lo;
}

// ---------- attention path ----------

__global__ void cvt_visit_kernel(const float* __restrict__ visit, unsigned short* __restrict__ out){
  int i = blockIdx.x*256 + threadIdx.x;
  if (i >= kBV*kNodes/8) return;
  const float4 a = *reinterpret_cast<const float4*>(visit + (size_t)i*8);
  const float4 b = *reinterpret_cast<const float4*>(visit + (size_t)i*8 + 4);
  unsigned short r[8] = {f2bf(a.x),f2bf(a.y),f2bf(a.z),f2bf(a.w),
                         f2bf(b.x),f2bf(b.y),f2bf(b.z),f2bf(b.w)};
  *reinterpret_cast<uint4*>(out + (size_t)i*8) = *reinterpret_cast<uint4*>(r);
}

// all 3 layers of alpha_w (4000x4000 f32) -> (4096x4000 bf16), pad rows zeroed
__global__ void cvtW_kernel(const float* __restrict__ W, unsigned short* __restrict__ out){
  int i = blockIdx.x*256 + threadIdx.x;
  constexpr int perL = kMPad*(kNodes/8);
  if (i >= kL*perL) return;
  int l = i / perL;
  int rem = i - l*perL;
  int row = rem / (kNodes/8);
  int col = (rem - row*(kNodes/8)) * 8;
  unsigned short r[8];
  if (row < kNodes){
    const float* p = W + (size_t)l*kNodes*kNodes + (size_t)row*kNodes + col;
    const float4 a = *reinterpret_cast<const float4*>(p);
    const float4 b = *reinterpret_cast<const float4*>(p + 4);
    r[0]=f2bf(a.x); r[1]=f2bf(a.y); r[2]=f2bf(a.z); r[3]=f2bf(a.w);
    r[4]=f2bf(b.x); r[5]=f2bf(b.y); r[6]=f2bf(b.z); r[7]=f2bf(b.w);
  } else {
    for (int q = 0; q < 8; q++) r[q] = 0;
  }
  *reinterpret_cast<uint4*>(out + (size_t)l*kMPad*kNodes + (size_t)row*kNodes + col)
      = *reinterpret_cast<uint4*>(r);
}

// S[lz](640 x 4096) = A(640 x Kslice) @ B_l(4096 x Kslice)^T ; lz = l*2+z
// global_load_lds staging (width 16), LDS rows [128][32] linear.
__global__ __launch_bounds__(256) void gemm_bt_bf16(const unsigned short* __restrict__ A,
    const unsigned short* __restrict__ Ball, float* __restrict__ Sbase){
  __shared__ unsigned short As[128*32];
  __shared__ unsigned short Bs[128*32];
  int bm = blockIdx.x, bn = blockIdx.y;
  int lz = blockIdx.z;
  int l = lz >> 1, z = lz & 1;
  const unsigned short* B = Ball + (size_t)l*kMPad*kNodes;
  float* C = Sbase + (size_t)lz*kBV*kMPad;
  int kBeg = z ? 2016 : 0;
  int kEnd = z ? kNodes : 2016;
  int t = threadIdx.x;
  int lane = t & 63, wave = t >> 6;
  int wm = (wave >> 1) * 64, wn = (wave & 1) * 64;
  int r = lane & 15, g = lane >> 4;

  // staging: wave w covers rows w*32 + q*16 + (lane>>2), q in {0,1}; 16B per lane
  int srow = wave*32 + (lane >> 2);
  int sk   = (lane & 3) * 8;
  const unsigned short* Ag = A + (size_t)(bm*128 + srow)*kNodes + kBeg + sk;
  const unsigned short* Bg = B + (size_t)(bn*128 + srow)*kNodes + kBeg + sk;
  unsigned short* AsB0 = &As[(wave*32    )*32];
  unsigned short* AsB1 = &As[(wave*32 + 16)*32];
  unsigned short* BsB0 = &Bs[(wave*32    )*32];
  unsigned short* BsB1 = &Bs[(wave*32 + 16)*32];
  const size_t rowStep = (size_t)16*kNodes;

  f32x4 acc[4][4];
#pragma unroll
  for (int i = 0; i < 4; i++)
#pragma unroll
    for (int j = 0; j < 4; j++) acc[i][j] = f32x4{0.f,0.f,0.f,0.f};

  for (int k0 = kBeg; k0 < kEnd; k0 += 32){
    __syncthreads();                     // previous iter's LDS reads done
    gload_lds16(Ag,           AsB0);
    gload_lds16(Ag + rowStep, AsB1);
    gload_lds16(Bg,           BsB0);
    gload_lds16(Bg + rowStep, BsB1);
    Ag += 32; Bg += 32;
    __syncthreads();                     // barrier drains vmcnt for gload_lds
    bf16x8 af[4], bf[4];
#pragma unroll
    for (int i = 0; i < 4; i++){
      af[i] = *reinterpret_cast<const bf16x8*>(&As[(wm + i*16 + r)*32 + g*8]);
      bf[i] = *reinterpret_cast<const bf16x8*>(&Bs[(wn + i*16 + r)*32 + g*8]);
    }
#pragma unroll
    for (int i = 0; i < 4; i++)
#pragma unroll
      for (int j = 0; j < 4; j++)
        acc[i][j] = __builtin_amdgcn_mfma_f32_16x16x32_bf16(af[i], bf[j], acc[i][j], 0, 0, 0);
  }
#pragma unroll
  for (int i = 0; i < 4; i++)
#pragma unroll
    for (int j = 0; j < 4; j++){
      int row = bm*128 + wm + i*16 + g*4;
      int col = bn*128 + wn + j*16 + r;
#pragma unroll
      for (int q = 0; q < 4; q++)
        C[(size_t)(row + q)*kMPad + col] = acc[i][j][q];
    }
}

// beta[l][bv] = tanh(visit[bv]·beta_w[l] + beta_b[l]) * exp(0.03*(V - v)), all layers
__global__ __launch_bounds__(256) void beta_all_kernel(const float* __restrict__ visit,
    const float* __restrict__ beta_w, const float* __restrict__ beta_b,
    float* __restrict__ beta){
  int wid = (blockIdx.x*256 + threadIdx.x) >> 6;
  int lane = threadIdx.x & 63;
  if (wid >= kL*kBV) return;
  int l = wid / kBV, bv = wid - l*kBV;
  const float* row = visit + (size_t)bv*kNodes;
  const float* bw = beta_w + (size_t)l*kNodes;
  float s = 0.f;
  for (int k = lane; k < kNodes; k += 64) s = fmaf(row[k], bw[k], s);
#pragma unroll
  for (int o = 32; o > 0; o >>= 1) s += __shfl_down(s, o);
  if (lane == 0){
    int v = bv % kV;
    float lam = __expf(0.03f * (float)(kV - v));
    beta[wid] = tanhf(s + beta_b[l]) * lam;
  }
}

// attn[l][b][m] = sum_v softmax_v(S0+S1) * beta[l,b,v]  (all layers)
__global__ __launch_bounds__(256) void attn_kernel(const float* __restrict__ S,
    const float* __restrict__ beta, float* __restrict__ attn){
  int idx = blockIdx.x*256 + threadIdx.x;
  if (idx >= kL*kB*kNodes) return;
  int l = idx / (kB*kNodes);
  int rem = idx - l*(kB*kNodes);
  int b = rem / kNodes;
  int m = rem - b*kNodes;
  const float* S0 = S + (size_t)(l*2)*kBV*kMPad + (size_t)b*kV*kMPad + m;
  const float* S1 = S0 + (size_t)kBV*kMPad;
  float vals[kV];
  float mx = -1e30f;
#pragma unroll
  for (int v = 0; v < kV; v++){
    float s = S0[(size_t)v*kMPad] + S1[(size_t)v*kMPad];
    vals[v] = s; mx = fmaxf(mx, s);
  }
  float se = 0.f, ws = 0.f;
  const float* bp = beta + l*kBV + b*kV;
#pragma unroll
  for (int v = 0; v < kV; v++){ float e = __expf(vals[v] - mx); se += e; ws = fmaf(e, bp[v], ws); }
  attn[idx] = ws / se;
}

// att_n[l][n] = attn[l][batch[n]][node_ids[n]] — collapse 2-deep random chain
__global__ void attn_gather_kernel(const int* __restrict__ batch,
    const int* __restrict__ node_ids, const float* __restrict__ attn,
    float* __restrict__ att_n){
  int idx = blockIdx.x*256 + threadIdx.x;
  if (idx >= kL*kN) return;
  int l = idx / kN, n = idx - l*kN;
  att_n[idx] = attn[(size_t)l*kB*kNodes + (size_t)batch[n]*kNodes + node_ids[n]];
}

// ---------- GNN layer ----------

__global__ __launch_bounds__(256) void agg_kernel(const int* __restrict__ starts,
    const int* __restrict__ perm, const int* __restrict__ src, const int* __restrict__ rel_ids,
    const float* __restrict__ att_n_l, const float* __restrict__ relterm_l,
    const float* __restrict__ x, float* __restrict__ agg){
  int wid = (blockIdx.x*256 + threadIdx.x) >> 6;
  int lane = threadIdx.x & 63;
  if (wid >= kN) return;
  int p0 = starts[wid], p1 = starts[wid+1];
  int c = lane*2;
  float a0 = 0.f, a1 = 0.f;
  for (int p = p0; p < p1; p++){
    int e = perm[p];
    int s = src[e];
    float at = att_n_l[s];
    float2 xv = *reinterpret_cast<const float2*>(&x[(size_t)s*kH + c]);
    float2 rt = *reinterpret_cast<const float2*>(&relterm_l[(size_t)rel_ids[e]*kH + c]);
    float m0 = fmaf(xv.x, at, rt.x); m0 = m0 > 0.f ? m0 : 0.f;
    float m1 = fmaf(xv.y, at, rt.y); m1 = m1 > 0.f ? m1 : 0.f;
    a0 += m0; a1 += m1;
  }
  *reinterpret_cast<float2*>(&agg[(size_t)wid*kH + c]) = float2{a0, a1};
}

__global__ __launch_bounds__(256) void nn_kernel(const float* __restrict__ agg,
    float* __restrict__ x, const float* __restrict__ nn_wT_l, const float* __restrict__ nn_b_l){
  __shared__ float rows[8][kH];
  int rb = blockIdx.x * 8;
  int t = threadIdx.x;
#pragma unroll
  for (int i = 0; i < 4; i++){
    int idx = t + i*256;
    int rr = idx >> 7, cc = idx & (kH-1);
    size_t gi = (size_t)(rb + rr)*kH + cc;
    rows[rr][cc] = agg[gi] + x[gi];
  }
  __syncthreads();
  int cc = t & (kH-1);
  int r0 = (t >> 7) * 4;
  float acc0 = 0.f, acc1 = 0.f, acc2 = 0.f, acc3 = 0.f;
#pragma unroll 8
  for (int k = 0; k < kH; k++){
    float w = nn_wT_l[k*kH + cc];
    acc0 = fmaf(rows[r0+0][k], w, acc0);
    acc1 = fmaf(rows[r0+1][k], w, acc1);
    acc2 = fmaf(rows[r0+2][k], w, acc2);
    acc3 = fmaf(rows[r0+3][k], w, acc3);
  }
  float b = nn_b_l[cc];
  x[(size_t)(rb+r0+0)*kH + cc] = fmaxf(acc0 + b, 0.f);
  x[(size_t)(rb+r0+1)*kH + cc] = fmaxf(acc1 + b, 0.f);
  x[(size_t)(rb+r0+2)*kH + cc] = fmaxf(acc2 + b, 0.f);
  x[(size_t)(rb+r0+3)*kH + cc] = fmaxf(acc3 + b, 0.f);
}

// ---------- readout (fused; no atomics) ----------

__global__ __launch_bounds__(128) void pool_part_kernel(const float* __restrict__ x,
    const int* __restrict__ ub, float* __restrict__ pp){
  int s = blockIdx.x, b = blockIdx.y, c = threadIdx.x;
  int lo = ub[b], len = ub[b+1] - lo;
  int i0 = lo + (int)(((long long)len * s) >> 3);
  int i1 = lo + (int)(((long long)len * (s+1)) >> 3);
  float acc = 0.f;
  for (int i = i0; i < i1; i++) acc += x[(size_t)i*kH + c];
  pp[(size_t)(b*8 + s)*kH + c] = acc;
}

__global__ __launch_bounds__(128) void xnode1_kernel(const float* __restrict__ ehr,
    const float* __restrict__ node_emb, float* __restrict__ pn, float* __restrict__ ps){
  int s = blockIdx.x, b = blockIdx.y, c = threadIdx.x;
  int n0 = s * (kNodes/8), n1 = n0 + (kNodes/8);
  float acc = 0.f, es = 0.f;
  for (int n = n0; n < n1; n++){
    float e = ehr[(size_t)b*kNodes + n];
    es += e;
    acc = fmaf(e, node_emb[(size_t)n*kH + c], acc);
  }
  pn[(size_t)(b*8 + s)*kH + c] = acc;
  if (c == 0) ps[b*8 + s] = es;
}

// xg-finish + xnode-finish + final MLP in one kernel
__global__ __launch_bounds__(128) void readout_kernel(const float* __restrict__ pp,
    const int* __restrict__ ub, const float* __restrict__ pn, const float* __restrict__ ps,
    const float* __restrict__ lin_wT, const float* __restrict__ lin_b,
    const float* __restrict__ mlp_w, const float* __restrict__ mlp_b,
    float* __restrict__ out){
  int b = blockIdx.x, h = threadIdx.x;
  __shared__ float v[2*kH];
  __shared__ float ts[kH];
  float s = 0.f;
#pragma unroll
  for (int q = 0; q < 8; q++) s += pp[(size_t)(b*8 + q)*kH + h];
  int len = ub[b+1] - ub[b]; if (len < 1) len = 1;
  v[h] = s / (float)len;
  float acc = 0.f, es = 0.f;
#pragma unroll
  for (int q = 0; q < 8; q++){
    acc += pn[(size_t)(b*8 + q)*kH + h];
    es  += ps[b*8 + q];
  }
  ts[h] = acc / es;
  __syncthreads();
  float r = lin_b[h];
#pragma unroll 8
  for (int k = 0; k < kH; k++) r = fmaf(ts[k], lin_wT[k*kH + h], r);
  v[kH + h] = r;
  __syncthreads();
  float o = mlp_b[h];
#pragma unroll 8
  for (int k = 0; k < 2*kH; k++) o = fmaf(v[k], mlp_w[(size_t)h*2*kH + k], o);
  out[b*kH + h] = o;
}

} // namespace

extern "C" void kernel_launch(void* const* d_in, const int* in_sizes, int n_in,
                              void* d_out, int out_size, void* d_ws, size_t ws_size,
                              hipStream_t stream){
  const int*   node_ids = (const int*)d_in[0];
  const int*   rel_ids  = (const int*)d_in[1];
  const int*   e_src    = (const int*)d_in[2];
  const int*   e_dst    = e_src + kE;
  const int*   batch    = (const int*)d_in[3];
  const float* visit    = (const float*)d_in[4];
  const float* ehr      = (const float*)d_in[5];
  const float* node_emb = (const float*)d_in[6];
  const float* rel_emb  = (const float*)d_in[7];
  const float* lin_w    = (const float*)d_in[8];
  const float* lin_b    = (const float*)d_in[9];
  const float* alpha_w  = (const float*)d_in[10];
  const float* beta_w   = (const float*)d_in[12];
  const float* beta_b   = (const float*)d_in[13];
  const float* wr_w     = (const float*)d_in[14];
  const float* wr_b     = (const float*)d_in[15];
  const float* nn_w     = (const float*)d_in[16];
  const float* nn_b     = (const float*)d_in[17];
  const float* mlp_w    = (const float*)d_in[18];
  const float* mlp_b    = (const float*)d_in[19];
  float* out = (float*)d_out;

  char* w = (char*)d_ws;
  auto alloc = [&](size_t bytes)->char*{
    char* p = w; w += (bytes + 255) & ~(size_t)255; return p;
  };
  int*   starts = (int*)  alloc((size_t)(kN+1)*4);
  int*   deg    = (int*)  alloc((size_t)kN*4);
  int*   bsum   = (int*)  alloc(256*4);
  int*   boffs  = (int*)  alloc(256*4);
  int*   ub     = (int*)  alloc((kB+1)*4);
  int*   perm   = (int*)  alloc((size_t)kE*4);
  unsigned short* rank = (unsigned short*)alloc((size_t)kE*2);
  unsigned int* hpart  = (unsigned int*)alloc((size_t)kNB*kN*4);   // becomes colOff in place
  float* embLin = (float*)alloc((size_t)kNodes*kH*4);
  float* relLin = (float*)alloc((size_t)kRels*kH*4);
  float* relterm= (float*)alloc((size_t)kL*kRels*kH*4);
  float* linwT  = (float*)alloc((size_t)kH*kH*4);
  float* nnwT   = (float*)alloc((size_t)kL*kH*kH*4);
  float* x      = (float*)alloc((size_t)kN*kH*4);
  float* agg    = (float*)alloc((size_t)kN*kH*4);
  unsigned short* visitbf = (unsigned short*)alloc((size_t)kBV*kNodes*2);
  unsigned short* awbf    = (unsigned short*)alloc((size_t)kL*kMPad*kNodes*2);
  float* S      = (float*)alloc((size_t)kL*2*kBV*kMPad*4);
  float* attn   = (float*)alloc((size_t)kL*kB*kNodes*4);
  float* att_n  = (float*)alloc((size_t)kL*kN*4);
  float* beta   = (float*)alloc((size_t)kL*kBV*4);
  float* pp     = (float*)alloc((size_t)kB*8*kH*4);
  float* pn     = (float*)alloc((size_t)kB*8*kH*4);
  float* ps     = (float*)alloc((size_t)kB*8*4);
  if ((size_t)(w - (char*)d_ws) > ws_size) return;   // ws too small: fail visibly

  // prep
  transpose_kernel<<<4, 256, 0, stream>>>(lin_w, nn_w, linwT, nnwT);
  proj_kernel<<<kNodes + kRels, 128, 0, stream>>>(node_emb, rel_emb, linwT, lin_b, embLin, relLin);
  gather_x0_kernel<<<(kN*kH)/256, 256, 0, stream>>>(node_ids, embLin, x);
  relterm_kernel<<<kL*kRels, 128, 0, stream>>>(relLin, wr_w, wr_b, relterm);

  // CSR build (no global atomics)
  csr_hist_kernel<<<dim3(kNB, 2), 256, 0, stream>>>(e_dst, rank, hpart);
  csr_col_kernel<<<(kN+255)/256, 256, 0, stream>>>(hpart, deg);
  scanA_kernel<<<(kN+255)/256, 256, 0, stream>>>(deg, starts, bsum);
  scanB_kernel<<<1, 128, 0, stream>>>(bsum, boffs, (kN+255)/256);
  scanC_kernel<<<(kN+255)/256, 256, 0, stream>>>(starts, boffs);
  csr_place_kernel<<<128, 256, 0, stream>>>(e_dst, starts, hpart, rank, perm);
  ub_kernel<<<1, 64, 0, stream>>>(batch, ub);

  // attention path (all layers batched)
  cvt_visit_kernel<<<(kBV*kNodes/8 + 255)/256, 256, 0, stream>>>(visit, visitbf);
  beta_all_kernel<<<kL*kBV/4, 256, 0, stream>>>(visit, beta_w, beta_b, beta);
  cvtW_kernel<<<(kL*kMPad*(kNodes/8) + 255)/256, 256, 0, stream>>>(alpha_w, awbf);
  gemm_bt_bf16<<<dim3(kBV/128, kMPad/128, kL*2), 256, 0, stream>>>(visitbf, awbf, S);
  attn_kernel<<<(kL*kB*kNodes + 255)/256, 256, 0, stream>>>(S, beta, attn);
  attn_gather_kernel<<<(kL*kN + 255)/256, 256, 0, stream>>>(batch, node_ids, attn, att_n);

  // GNN layers
  for (int l = 0; l < kL; l++){
    agg_kernel<<<kN/4, 256, 0, stream>>>(starts, perm, e_src, rel_ids,
        att_n + (size_t)l*kN, relterm + (size_t)l*kRels*kH, x, agg);
    nn_kernel<<<kN/8, 256, 0, stream>>>(agg, x, nnwT + (size_t)l*kH*kH, nn_b + (size_t)l*kH);
  }

  // readout
  pool_part_kernel<<<dim3(8, kB), 128, 0, stream>>>(x, ub, pp);
  xnode1_kernel<<<dim3(8, kB), 128, 0, stream>>>(ehr, node_emb, pn, ps);
  readout_kernel<<<kB, 128, 0, stream>>>(pp, ub, pn, ps, linwT, lin_b, mlp_w, mlp_b, out);
}

// Round 6
// 610.731 us; speedup vs baseline: 2.0446x; 1.0362x over previous
//
#include <hip/hip_runtime.h>

namespace {

constexpr int kNodes = 4000;        // node-TYPE vocabulary (attn/alpha space)
constexpr int kRels  = 400;
constexpr int kB     = 32;
constexpr int kV     = 20;
constexpr int kN     = 32000;       // graph nodes (CSR space)
constexpr int kE     = 256000;
constexpr int kH     = 128;
constexpr int kL     = 3;
constexpr int kMPad  = 4096;        // alpha_w m-dim padded
constexpr int kKPad  = 4096;        // K padded (zeros beyond 4000) so BK=64 divides
constexpr int kBV    = kB * kV;     // 640
constexpr int kNB    = 32;          // CSR sort blocks
constexpr int kChunk = kE / kNB;    // 8000 edges per sort block
constexpr int kHalf  = 16000;       // bins per LDS pass (64KB LDS); 2*kHalf == kN

typedef __attribute__((ext_vector_type(8))) short bf16x8;
typedef __attribute__((ext_vector_type(4))) float f32x4;

__device__ inline unsigned short f2bf(float f){
  unsigned int u = __float_as_uint(f);
  u += 0x7FFFu + ((u >> 16) & 1u);      // round-to-nearest-even
  return (unsigned short)(u >> 16);
}

// global->LDS direct copy, 16B per lane, dest = wave-uniform base + lane*16
__device__ inline void gload_lds16(const unsigned short* g, unsigned short* l){
  __builtin_amdgcn_global_load_lds(
      (const __attribute__((address_space(1))) unsigned int*)(g),
      (__attribute__((address_space(3))) unsigned int*)(l),
      16, 0, 0);
}

// ---------- prep kernels ----------

__global__ void transpose_kernel(const float* __restrict__ lin_w, const float* __restrict__ nn_w,
                                 float* __restrict__ lin_wT, float* __restrict__ nn_wT){
  int m = blockIdx.x;
  const float* in = (m == 0) ? lin_w : nn_w + (size_t)(m-1)*kH*kH;
  float* out      = (m == 0) ? lin_wT : nn_wT + (size_t)(m-1)*kH*kH;
  for (int i = threadIdx.x; i < kH*kH; i += blockDim.x){
    int r = i >> 7, c = i & (kH-1);
    out[c*kH + r] = in[i];
  }
}

__global__ __launch_bounds__(128) void proj_kernel(const float* __restrict__ node_emb,
    const float* __restrict__ rel_emb, const float* __restrict__ lin_wT,
    const float* __restrict__ lin_b, float* __restrict__ emb_lin, float* __restrict__ rel_lin){
  int row = blockIdx.x;
  const float* src; float* dst;
  if (row < kNodes){ src = node_emb + (size_t)row*kH; dst = emb_lin + (size_t)row*kH; }
  else             { src = rel_emb + (size_t)(row-kNodes)*kH; dst = rel_lin + (size_t)(row-kNodes)*kH; }
  __shared__ float rs[kH];
  int h = threadIdx.x;
  rs[h] = src[h];
  __syncthreads();
  float acc = lin_b[h];
#pragma unroll 8
  for (int k = 0; k < kH; k++) acc = fmaf(rs[k], lin_wT[k*kH + h], acc);
  dst[h] = acc;
}

__global__ void gather_x0_kernel(const int* __restrict__ node_ids,
                                 const float* __restrict__ emb_lin, float* __restrict__ x){
  int idx = blockIdx.x*256 + threadIdx.x;
  if (idx < kN*kH){
    int i = idx >> 7, c = idx & (kH-1);
    x[idx] = emb_lin[(size_t)node_ids[i]*kH + c];
  }
}

__global__ __launch_bounds__(128) void relterm_kernel(const float* __restrict__ rel_lin,
    const float* __restrict__ wr_w, const float* __restrict__ wr_b, float* __restrict__ relterm){
  int l = blockIdx.x / kRels, r = blockIdx.x % kRels;
  int t = threadIdx.x;
  float rl = rel_lin[(size_t)r*kH + t];
  __shared__ float red[kH];
  red[t] = rl * wr_w[l*kH + t];
  __syncthreads();
  for (int o = 64; o > 0; o >>= 1){
    if (t < o) red[t] += red[t+o];
    __syncthreads();
  }
  float w = red[0] + wr_b[l];
  relterm[((size_t)l*kRels + r)*kH + t] = w * rl;
}

// ---------- CSR build over kN graph nodes (no global atomics) ----------

__global__ __launch_bounds__(256) void csr_hist_kernel(const int* __restrict__ dst,
    unsigned short* __restrict__ rank, unsigned int* __restrict__ hpart){
  __shared__ unsigned int hb[kHalf];
  int p = blockIdx.x;
  int base = blockIdx.y * kHalf;
  int t = threadIdx.x;
  for (int i = t; i < kHalf; i += 256) hb[i] = 0u;
  __syncthreads();
  for (int i = t; i < kChunk; i += 256){
    int e = p*kChunk + i;
    int d = dst[e];
    int rel = d - base;
    if ((unsigned)rel < (unsigned)kHalf){
      rank[e] = (unsigned short)atomicAdd(&hb[rel], 1u);
    }
  }
  __syncthreads();
  for (int i = t; i < kHalf; i += 256)
    hpart[(size_t)p*kN + base + i] = hb[i];
}

__global__ __launch_bounds__(256) void csr_col_kernel(unsigned int* __restrict__ hpart,
    int* __restrict__ deg){
  int bin = blockIdx.x*256 + threadIdx.x;
  if (bin >= kN) return;
  unsigned int s = 0;
#pragma unroll
  for (int p = 0; p < kNB; p++){
    size_t idx = (size_t)p*kN + bin;
    unsigned int v = hpart[idx];
    hpart[idx] = s;
    s += v;
  }
  deg[bin] = (int)s;
}

__global__ __launch_bounds__(256) void scanA_kernel(const int* __restrict__ deg,
    int* __restrict__ starts, int* __restrict__ bsum){
  __shared__ int buf[256];
  int gid = blockIdx.x*256 + threadIdx.x;
  int t = threadIdx.x;
  int v = (gid < kN) ? deg[gid] : 0;
  buf[t] = v;
  __syncthreads();
  for (int o = 1; o < 256; o <<= 1){
    int add = (t >= o) ? buf[t-o] : 0;
    __syncthreads();
    buf[t] += add;
    __syncthreads();
  }
  if (gid < kN) starts[gid] = buf[t] - v;
  if (t == 255) bsum[blockIdx.x] = buf[255];
}

__global__ __launch_bounds__(128) void scanB_kernel(const int* __restrict__ bsum,
    int* __restrict__ boffs, int nblk){
  __shared__ int buf[128];
  int t = threadIdx.x;
  int v = (t < nblk) ? bsum[t] : 0;
  buf[t] = v;
  __syncthreads();
  for (int o = 1; o < 128; o <<= 1){
    int add = (t >= o) ? buf[t-o] : 0;
    __syncthreads();
    buf[t] += add;
    __syncthreads();
  }
  if (t < nblk) boffs[t] = buf[t] - v;
}

__global__ __launch_bounds__(256) void scanC_kernel(int* __restrict__ starts,
    const int* __restrict__ boffs){
  int gid = blockIdx.x*256 + threadIdx.x;
  if (gid < kN) starts[gid] += boffs[blockIdx.x];
  if (gid == kN-1) starts[kN] = kE;
}

__global__ __launch_bounds__(256) void csr_place_kernel(const int* __restrict__ dst,
    const int* __restrict__ starts, const unsigned int* __restrict__ colOff,
    const unsigned short* __restrict__ rank, int* __restrict__ perm){
  int blk = blockIdx.x;                 // 128 blocks x 2000 edges
  int p = blk >> 2;                     // 4 blocks per sort chunk
  for (int i = threadIdx.x; i < 2000; i += 256){
    int e = blk*2000 + i;
    int d = dst[e];
    int pos = starts[d] + (int)colOff[(size_t)p*kN + d] + (int)rank[e];
    perm[pos] = e;
  }
}

__global__ void ub_kernel(const int* __restrict__ batch, int* __restrict__ ub){
  int j = threadIdx.x;
  if (j > kB) return;
  int lo = 0, hi = kN;
  while (lo < hi){
    int mid = (lo + hi) >> 1;
    if (batch[mid] < j) lo = mid + 1; else hi = mid;
  }
  ub[j] = lo;
}

// ---------- attention path ----------

// visit (640 x 4000 f32) -> visitbf (640 x 4096 bf16), pad cols zeroed
__global__ void cvt_visit_kernel(const float* __restrict__ visit, unsigned short* __restrict__ out){
  int i = blockIdx.x*256 + threadIdx.x;     // vec8 over 640*512
  if (i >= kBV*(kKPad/8)) return;
  int row = i >> 9;                          // / 512
  int col = (i & 511) * 8;
  unsigned short r[8];
  if (col < kNodes){
    const float* p = visit + (size_t)row*kNodes + col;
    const float4 a = *reinterpret_cast<const float4*>(p);
    const float4 b = *reinterpret_cast<const float4*>(p + 4);
    r[0]=f2bf(a.x); r[1]=f2bf(a.y); r[2]=f2bf(a.z); r[3]=f2bf(a.w);
    r[4]=f2bf(b.x); r[5]=f2bf(b.y); r[6]=f2bf(b.z); r[7]=f2bf(b.w);
  } else {
    for (int q = 0; q < 8; q++) r[q] = 0;
  }
  *reinterpret_cast<uint4*>(out + (size_t)row*kKPad + col) = *reinterpret_cast<uint4*>(r);
}

// all 3 layers of alpha_w (4000x4000 f32) -> (4096 x 4096 bf16), pads zeroed
__global__ void cvtW_kernel(const float* __restrict__ W, unsigned short* __restrict__ out){
  int i = blockIdx.x*256 + threadIdx.x;
  constexpr int perL = kMPad*(kKPad/8);
  if (i >= kL*perL) return;
  int l = i / perL;
  int rem = i - l*perL;
  int row = rem >> 9;
  int col = (rem & 511) * 8;
  unsigned short r[8];
  if (row < kNodes && col < kNodes){
    const float* p = W + (size_t)l*kNodes*kNodes + (size_t)row*kNodes + col;
    const float4 a = *reinterpret_cast<const float4*>(p);
    const float4 b = *reinterpret_cast<const float4*>(p + 4);
    r[0]=f2bf(a.x); r[1]=f2bf(a.y); r[2]=f2bf(a.z); r[3]=f2bf(a.w);
    r[4]=f2bf(b.x); r[5]=f2bf(b.y); r[6]=f2bf(b.z); r[7]=f2bf(b.w);
  } else {
    for (int q = 0; q < 8; q++) r[q] = 0;
  }
  *reinterpret_cast<uint4*>(out + (size_t)l*kMPad*kKPad + (size_t)row*kKPad + col)
      = *reinterpret_cast<uint4*>(r);
}

// S[lz](640 x 4096) = A(640 x 2048-slice) @ B_l(4096 x 2048-slice)^T ; lz = l*2+z
// BK=64; global_load_lds with source-pre-swizzle (slot ^= row&7) + swizzled ds_read;
// XCD-chunked bijective block swizzle, bm-fastest for B-panel L2 reuse.
__global__ __launch_bounds__(256) void gemm_bt_bf16(const unsigned short* __restrict__ A,
    const unsigned short* __restrict__ Ball, float* __restrict__ Sbase){
  __shared__ unsigned short As[128*64];
  __shared__ unsigned short Bs[128*64];
  // 960 blocks; 960 % 8 == 0 -> chunk=120 per XCD
  int wg = (blockIdx.x & 7)*120 + (blockIdx.x >> 3);
  int lz = wg / 160;
  int rem = wg - lz*160;
  int bn = rem / 5;
  int bm = rem - bn*5;
  int l = lz >> 1, z = lz & 1;
  const unsigned short* B = Ball + (size_t)l*kMPad*kKPad;
  float* C = Sbase + (size_t)lz*kBV*kMPad;
  int kBase = z * 2048;

  int t = threadIdx.x;
  int lane = t & 63, wave = t >> 6;
  int wm = (wave >> 1) * 64, wn = (wave & 1) * 64;
  int r = lane & 15, g = lane >> 4;

  // staging: wave stages rows [wave*32, wave*32+32) in 4 chunks of 8 rows.
  // lane: ri = lane>>3 (row in chunk), s = lane&7 (16B slot in 128B row).
  // LDS dest linear; global source k-slot pre-swizzled: slot' = s ^ ri.
  int ri = lane >> 3, s = lane & 7;
  int koff = ((s ^ ri) << 3);           // elements
  const unsigned short* Ag = A + (size_t)(bm*128 + wave*32 + ri)*kKPad + kBase + koff;
  const unsigned short* Bg = B + (size_t)(bn*128 + wave*32 + ri)*kKPad + kBase + koff;
  const size_t chunkStep = (size_t)8*kKPad;   // 8 rows

  f32x4 acc[4][4];
#pragma unroll
  for (int i = 0; i < 4; i++)
#pragma unroll
    for (int j = 0; j < 4; j++) acc[i][j] = f32x4{0.f,0.f,0.f,0.f};

  for (int k0 = 0; k0 < 2048; k0 += 64){
    __syncthreads();                     // previous iter's LDS reads done
#pragma unroll
    for (int c = 0; c < 4; c++){
      gload_lds16(Ag + c*chunkStep, &As[(wave*32 + c*8)*64]);
      gload_lds16(Bg + c*chunkStep, &Bs[(wave*32 + c*8)*64]);
    }
    Ag += 64; Bg += 64;
    __syncthreads();                     // barrier drains vmcnt for gload_lds
#pragma unroll
    for (int ksub = 0; ksub < 2; ksub++){
      bf16x8 af[4], bf[4];
#pragma unroll
      for (int i = 0; i < 4; i++){
        int arow = wm + i*16 + r;
        int brow = wn + i*16 + r;
        int slot = ((ksub << 2) + g);
        af[i] = *reinterpret_cast<const bf16x8*>(&As[arow*64 + ((slot ^ (arow & 7)) << 3)]);
        bf[i] = *reinterpret_cast<const bf16x8*>(&Bs[brow*64 + ((slot ^ (brow & 7)) << 3)]);
      }
#pragma unroll
      for (int i = 0; i < 4; i++)
#pragma unroll
        for (int j = 0; j < 4; j++)
          acc[i][j] = __builtin_amdgcn_mfma_f32_16x16x32_bf16(af[i], bf[j], acc[i][j], 0, 0, 0);
    }
  }
#pragma unroll
  for (int i = 0; i < 4; i++)
#pragma unroll
    for (int j = 0; j < 4; j++){
      int row = bm*128 + wm + i*16 + g*4;
      int col = bn*128 + wn + j*16 + r;
#pragma unroll
      for (int q = 0; q < 4; q++)
        C[(size_t)(row + q)*kMPad + col] = acc[i][j][q];
    }
}

// beta[l][bv] = tanh(visit[bv]·beta_w[l] + beta_b[l]) * exp(0.03*(V - v)), all layers
__global__ __launch_bounds__(256) void beta_all_kernel(const float* __restrict__ visit,
    const float* __restrict__ beta_w, const float* __restrict__ beta_b,
    float* __restrict__ beta){
  int wid = (blockIdx.x*256 + threadIdx.x) >> 6;
  int lane = threadIdx.x & 63;
  if (wid >= kL*kBV) return;
  int l = wid / kBV, bv = wid - l*kBV;
  const float* row = visit + (size_t)bv*kNodes;
  const float* bw = beta_w + (size_t)l*kNodes;
  float s = 0.f;
  for (int k = lane; k < kNodes; k += 64) s = fmaf(row[k], bw[k], s);
#pragma unroll
  for (int o = 32; o > 0; o >>= 1) s += __shfl_down(s, o);
  if (lane == 0){
    int v = bv % kV;
    float lam = __expf(0.03f * (float)(kV - v));
    beta[wid] = tanhf(s + beta_b[l]) * lam;
  }
}

// attn[l][b][m] = sum_v softmax_v(S0+S1) * beta[l,b,v]  (all layers)
__global__ __launch_bounds__(256) void attn_kernel(const float* __restrict__ S,
    const float* __restrict__ beta, float* __restrict__ attn){
  int idx = blockIdx.x*256 + threadIdx.x;
  if (idx >= kL*kB*kNodes) return;
  int l = idx / (kB*kNodes);
  int rem = idx - l*(kB*kNodes);
  int b = rem / kNodes;
  int m = rem - b*kNodes;
  const float* S0 = S + (size_t)(l*2)*kBV*kMPad + (size_t)b*kV*kMPad + m;
  const float* S1 = S0 + (size_t)kBV*kMPad;
  float vals[kV];
  float mx = -1e30f;
#pragma unroll
  for (int v = 0; v < kV; v++){
    float s = S0[(size_t)v*kMPad] + S1[(size_t)v*kMPad];
    vals[v] = s; mx = fmaxf(mx, s);
  }
  float se = 0.f, ws = 0.f;
  const float* bp = beta + l*kBV + b*kV;
#pragma unroll
  for (int v = 0; v < kV; v++){ float e = __expf(vals[v] - mx); se += e; ws = fmaf(e, bp[v], ws); }
  attn[idx] = ws / se;
}

// att_n[l][n] = attn[l][batch[n]][node_ids[n]] — collapse 2-deep random chain
__global__ void attn_gather_kernel(const int* __restrict__ batch,
    const int* __restrict__ node_ids, const float* __restrict__ attn,
    float* __restrict__ att_n){
  int idx = blockIdx.x*256 + threadIdx.x;
  if (idx >= kL*kN) return;
  int l = idx / kN, n = idx - l*kN;
  att_n[idx] = attn[(size_t)l*kB*kNodes + (size_t)batch[n]*kNodes + node_ids[n]];
}

// ---------- GNN layer ----------

__global__ __launch_bounds__(256) void agg_kernel(const int* __restrict__ starts,
    const int* __restrict__ perm, const int* __restrict__ src, const int* __restrict__ rel_ids,
    const float* __restrict__ att_n_l, const float* __restrict__ relterm_l,
    const float* __restrict__ x, float* __restrict__ agg){
  int wid = (blockIdx.x*256 + threadIdx.x) >> 6;
  int lane = threadIdx.x & 63;
  if (wid >= kN) return;
  int p0 = starts[wid], p1 = starts[wid+1];
  int c = lane*2;
  float a0 = 0.f, a1 = 0.f;
  for (int p = p0; p < p1; p++){
    int e = perm[p];
    int s = src[e];
    float at = att_n_l[s];
    float2 xv = *reinterpret_cast<const float2*>(&x[(size_t)s*kH + c]);
    float2 rt = *reinterpret_cast<const float2*>(&relterm_l[(size_t)rel_ids[e]*kH + c]);
    float m0 = fmaf(xv.x, at, rt.x); m0 = m0 > 0.f ? m0 : 0.f;
    float m1 = fmaf(xv.y, at, rt.y); m1 = m1 > 0.f ? m1 : 0.f;
    a0 += m0; a1 += m1;
  }
  *reinterpret_cast<float2*>(&agg[(size_t)wid*kH + c]) = float2{a0, a1};
}

__global__ __launch_bounds__(256) void nn_kernel(const float* __restrict__ agg,
    float* __restrict__ x, const float* __restrict__ nn_wT_l, const float* __restrict__ nn_b_l){
  __shared__ float rows[8][kH];
  int rb = blockIdx.x * 8;
  int t = threadIdx.x;
#pragma unroll
  for (int i = 0; i < 4; i++){
    int idx = t + i*256;
    int rr = idx >> 7, cc = idx & (kH-1);
    size_t gi = (size_t)(rb + rr)*kH + cc;
    rows[rr][cc] = agg[gi] + x[gi];
  }
  __syncthreads();
  int cc = t & (kH-1);
  int r0 = (t >> 7) * 4;
  float acc0 = 0.f, acc1 = 0.f, acc2 = 0.f, acc3 = 0.f;
#pragma unroll 8
  for (int k = 0; k < kH; k++){
    float w = nn_wT_l[k*kH + cc];
    acc0 = fmaf(rows[r0+0][k], w, acc0);
    acc1 = fmaf(rows[r0+1][k], w, acc1);
    acc2 = fmaf(rows[r0+2][k], w, acc2);
    acc3 = fmaf(rows[r0+3][k], w, acc3);
  }
  float b = nn_b_l[cc];
  x[(size_t)(rb+r0+0)*kH + cc] = fmaxf(acc0 + b, 0.f);
  x[(size_t)(rb+r0+1)*kH + cc] = fmaxf(acc1 + b, 0.f);
  x[(size_t)(rb+r0+2)*kH + cc] = fmaxf(acc2 + b, 0.f);
  x[(size_t)(rb+r0+3)*kH + cc] = fmaxf(acc3 + b, 0.f);
}

// ---------- readout (fused; no atomics) ----------

__global__ __launch_bounds__(128) void pool_part_kernel(const float* __restrict__ x,
    const int* __restrict__ ub, float* __restrict__ pp){
  int s = blockIdx.x, b = blockIdx.y, c = threadIdx.x;
  int lo = ub[b], len = ub[b+1] - lo;
  int i0 = lo + (int)(((long long)len * s) >> 3);
  int i1 = lo + (int)(((long long)len * (s+1)) >> 3);
  float acc = 0.f;
  for (int i = i0; i < i1; i++) acc += x[(size_t)i*kH + c];
  pp[(size_t)(b*8 + s)*kH + c] = acc;
}

__global__ __launch_bounds__(128) void xnode1_kernel(const float* __restrict__ ehr,
    const float* __restrict__ node_emb, float* __restrict__ pn, float* __restrict__ ps){
  int s = blockIdx.x, b = blockIdx.y, c = threadIdx.x;
  int n0 = s * (kNodes/8), n1 = n0 + (kNodes/8);
  float acc = 0.f, es = 0.f;
  for (int n = n0; n < n1; n++){
    float e = ehr[(size_t)b*kNodes + n];
    es += e;
    acc = fmaf(e, node_emb[(size_t)n*kH + c], acc);
  }
  pn[(size_t)(b*8 + s)*kH + c] = acc;
  if (c == 0) ps[b*8 + s] = es;
}

// xg-finish + xnode-finish + final MLP in one kernel
__global__ __launch_bounds__(128) void readout_kernel(const float* __restrict__ pp,
    const int* __restrict__ ub, const float* __restrict__ pn, const float* __restrict__ ps,
    const float* __restrict__ lin_wT, const float* __restrict__ lin_b,
    const float* __restrict__ mlp_w, const float* __restrict__ mlp_b,
    float* __restrict__ out){
  int b = blockIdx.x, h = threadIdx.x;
  __shared__ float v[2*kH];
  __shared__ float ts[kH];
  float s = 0.f;
#pragma unroll
  for (int q = 0; q < 8; q++) s += pp[(size_t)(b*8 + q)*kH + h];
  int len = ub[b+1] - ub[b]; if (len < 1) len = 1;
  v[h] = s / (float)len;
  float acc = 0.f, es = 0.f;
#pragma unroll
  for (int q = 0; q < 8; q++){
    acc += pn[(size_t)(b*8 + q)*kH + h];
    es  += ps[b*8 + q];
  }
  ts[h] = acc / es;
  __syncthreads();
  float r = lin_b[h];
#pragma unroll 8
  for (int k = 0; k < kH; k++) r = fmaf(ts[k], lin_wT[k*kH + h], r);
  v[kH + h] = r;
  __syncthreads();
  float o = mlp_b[h];
#pragma unroll 8
  for (int k = 0; k < 2*kH; k++) o = fmaf(v[k], mlp_w[(size_t)h*2*kH + k], o);
  out[b*kH + h] = o;
}

} // namespace

extern "C" void kernel_launch(void* const* d_in, const int* in_sizes, int n_in,
                              void* d_out, int out_size, void* d_ws, size_t ws_size,
                              hipStream_t stream){
  const int*   node_ids = (const int*)d_in[0];
  const int*   rel_ids  = (const int*)d_in[1];
  const int*   e_src    = (const int*)d_in[2];
  const int*   e_dst    = e_src + kE;
  const int*   batch    = (const int*)d_in[3];
  const float* visit    = (const float*)d_in[4];
  const float* ehr      = (const float*)d_in[5];
  const float* node_emb = (const float*)d_in[6];
  const float* rel_emb  = (const float*)d_in[7];
  const float* lin_w    = (const float*)d_in[8];
  const float* lin_b    = (const float*)d_in[9];
  const float* alpha_w  = (const float*)d_in[10];
  const float* beta_w   = (const float*)d_in[12];
  const float* beta_b   = (const float*)d_in[13];
  const float* wr_w     = (const float*)d_in[14];
  const float* wr_b     = (const float*)d_in[15];
  const float* nn_w     = (const float*)d_in[16];
  const float* nn_b     = (const float*)d_in[17];
  const float* mlp_w    = (const float*)d_in[18];
  const float* mlp_b    = (const float*)d_in[19];
  float* out = (float*)d_out;

  char* w = (char*)d_ws;
  auto alloc = [&](size_t bytes)->char*{
    char* p = w; w += (bytes + 255) & ~(size_t)255; return p;
  };
  int*   starts = (int*)  alloc((size_t)(kN+1)*4);
  int*   deg    = (int*)  alloc((size_t)kN*4);
  int*   bsum   = (int*)  alloc(256*4);
  int*   boffs  = (int*)  alloc(256*4);
  int*   ub     = (int*)  alloc((kB+1)*4);
  int*   perm   = (int*)  alloc((size_t)kE*4);
  unsigned short* rank = (unsigned short*)alloc((size_t)kE*2);
  unsigned int* hpart  = (unsigned int*)alloc((size_t)kNB*kN*4);   // becomes colOff in place
  float* embLin = (float*)alloc((size_t)kNodes*kH*4);
  float* relLin = (float*)alloc((size_t)kRels*kH*4);
  float* relterm= (float*)alloc((size_t)kL*kRels*kH*4);
  float* linwT  = (float*)alloc((size_t)kH*kH*4);
  float* nnwT   = (float*)alloc((size_t)kL*kH*kH*4);
  float* x      = (float*)alloc((size_t)kN*kH*4);
  float* agg    = (float*)alloc((size_t)kN*kH*4);
  unsigned short* visitbf = (unsigned short*)alloc((size_t)kBV*kKPad*2);
  unsigned short* awbf    = (unsigned short*)alloc((size_t)kL*kMPad*kKPad*2);
  float* S      = (float*)alloc((size_t)kL*2*kBV*kMPad*4);
  float* attn   = (float*)alloc((size_t)kL*kB*kNodes*4);
  float* att_n  = (float*)alloc((size_t)kL*kN*4);
  float* beta   = (float*)alloc((size_t)kL*kBV*4);
  float* pp     = (float*)alloc((size_t)kB*8*kH*4);
  float* pn     = (float*)alloc((size_t)kB*8*kH*4);
  float* ps     = (float*)alloc((size_t)kB*8*4);
  if ((size_t)(w - (char*)d_ws) > ws_size) return;   // ws too small: fail visibly

  // prep
  transpose_kernel<<<4, 256, 0, stream>>>(lin_w, nn_w, linwT, nnwT);
  proj_kernel<<<kNodes + kRels, 128, 0, stream>>>(node_emb, rel_emb, linwT, lin_b, embLin, relLin);
  gather_x0_kernel<<<(kN*kH)/256, 256, 0, stream>>>(node_ids, embLin, x);
  relterm_kernel<<<kL*kRels, 128, 0, stream>>>(relLin, wr_w, wr_b, relterm);

  // CSR build (no global atomics)
  csr_hist_kernel<<<dim3(kNB, 2), 256, 0, stream>>>(e_dst, rank, hpart);
  csr_col_kernel<<<(kN+255)/256, 256, 0, stream>>>(hpart, deg);
  scanA_kernel<<<(kN+255)/256, 256, 0, stream>>>(deg, starts, bsum);
  scanB_kernel<<<1, 128, 0, stream>>>(bsum, boffs, (kN+255)/256);
  scanC_kernel<<<(kN+255)/256, 256, 0, stream>>>(starts, boffs);
  csr_place_kernel<<<128, 256, 0, stream>>>(e_dst, starts, hpart, rank, perm);
  ub_kernel<<<1, 64, 0, stream>>>(batch, ub);

  // attention path (all layers batched)
  cvt_visit_kernel<<<(kBV*(kKPad/8) + 255)/256, 256, 0, stream>>>(visit, visitbf);
  beta_all_kernel<<<kL*kBV/4, 256, 0, stream>>>(visit, beta_w, beta_b, beta);
  cvtW_kernel<<<(kL*kMPad*(kKPad/8) + 255)/256, 256, 0, stream>>>(alpha_w, awbf);
  gemm_bt_bf16<<<960, 256, 0, stream>>>(visitbf, awbf, S);
  attn_kernel<<<(kL*kB*kNodes + 255)/256, 256, 0, stream>>>(S, beta, attn);
  attn_gather_kernel<<<(kL*kN + 255)/256, 256, 0, stream>>>(batch, node_ids, attn, att_n);

  // GNN layers
  for (int l = 0; l < kL; l++){
    agg_kernel<<<kN/4, 256, 0, stream>>>(starts, perm, e_src, rel_ids,
        att_n + (size_t)l*kN, relterm + (size_t)l*kRels*kH, x, agg);
    nn_kernel<<<kN/8, 256, 0, stream>>>(agg, x, nnwT + (size_t)l*kH*kH, nn_b + (size_t)l*kH);
  }

  // readout
  pool_part_kernel<<<dim3(8, kB), 128, 0, stream>>>(x, ub, pp);
  xnode1_kernel<<<dim3(8, kB), 128, 0, stream>>>(ehr, node_emb, pn, ps);
  readout_kernel<<<kB, 128, 0, stream>>>(pp, ub, pn, ps, linwT, lin_b, mlp_w, mlp_b, out);
}

// Round 7
// 598.292 us; speedup vs baseline: 2.0871x; 1.0208x over previous
//
#include <hip/hip_runtime.h>

namespace {

constexpr int kNodes = 4000;        // node-TYPE vocabulary (attn/alpha space)
constexpr int kRels  = 400;
constexpr int kB     = 32;
constexpr int kV     = 20;
constexpr int kN     = 32000;       // graph nodes (CSR space)
constexpr int kE     = 256000;
constexpr int kH     = 128;
constexpr int kL     = 3;
constexpr int kMPad  = 4096;        // alpha_w m-dim padded
constexpr int kKPad  = 4096;        // K padded (zeros beyond 4000) so BK=64 divides
constexpr int kBV    = kB * kV;     // 640
constexpr int kNB    = 32;          // CSR sort blocks
constexpr int kChunk = kE / kNB;    // 8000 edges per sort block
constexpr int kHalf  = 16000;       // bins per LDS pass (64KB LDS); 2*kHalf == kN

typedef __attribute__((ext_vector_type(8))) short bf16x8;
typedef __attribute__((ext_vector_type(4))) float f32x4;

__device__ inline unsigned short f2bf(float f){
  unsigned int u = __float_as_uint(f);
  u += 0x7FFFu + ((u >> 16) & 1u);      // round-to-nearest-even
  return (unsigned short)(u >> 16);
}

// global->LDS direct copy, 16B per lane, dest = wave-uniform base + lane*16
__device__ inline void gload_lds16(const unsigned short* g, unsigned short* l){
  __builtin_amdgcn_global_load_lds(
      (const __attribute__((address_space(1))) unsigned int*)(g),
      (__attribute__((address_space(3))) unsigned int*)(l),
      16, 0, 0);
}

// ---------- prep kernels ----------

__global__ void transpose_kernel(const float* __restrict__ lin_w, const float* __restrict__ nn_w,
                                 float* __restrict__ lin_wT, float* __restrict__ nn_wT){
  int m = blockIdx.x;
  const float* in = (m == 0) ? lin_w : nn_w + (size_t)(m-1)*kH*kH;
  float* out      = (m == 0) ? lin_wT : nn_wT + (size_t)(m-1)*kH*kH;
  for (int i = threadIdx.x; i < kH*kH; i += blockDim.x){
    int r = i >> 7, c = i & (kH-1);
    out[c*kH + r] = in[i];
  }
}

__global__ __launch_bounds__(128) void proj_kernel(const float* __restrict__ node_emb,
    const float* __restrict__ rel_emb, const float* __restrict__ lin_wT,
    const float* __restrict__ lin_b, float* __restrict__ emb_lin, float* __restrict__ rel_lin){
  int row = blockIdx.x;
  const float* src; float* dst;
  if (row < kNodes){ src = node_emb + (size_t)row*kH; dst = emb_lin + (size_t)row*kH; }
  else             { src = rel_emb + (size_t)(row-kNodes)*kH; dst = rel_lin + (size_t)(row-kNodes)*kH; }
  __shared__ float rs[kH];
  int h = threadIdx.x;
  rs[h] = src[h];
  __syncthreads();
  float acc = lin_b[h];
#pragma unroll 8
  for (int k = 0; k < kH; k++) acc = fmaf(rs[k], lin_wT[k*kH + h], acc);
  dst[h] = acc;
}

__global__ void gather_x0_kernel(const int* __restrict__ node_ids,
                                 const float* __restrict__ emb_lin, float* __restrict__ x,
                                 unsigned short* __restrict__ xbf){
  int idx = blockIdx.x*256 + threadIdx.x;
  if (idx < kN*kH){
    int i = idx >> 7, c = idx & (kH-1);
    float v = emb_lin[(size_t)node_ids[i]*kH + c];
    x[idx] = v;
    xbf[idx] = f2bf(v);
  }
}

__global__ __launch_bounds__(128) void relterm_kernel(const float* __restrict__ rel_lin,
    const float* __restrict__ wr_w, const float* __restrict__ wr_b, float* __restrict__ relterm){
  int l = blockIdx.x / kRels, r = blockIdx.x % kRels;
  int t = threadIdx.x;
  float rl = rel_lin[(size_t)r*kH + t];
  __shared__ float red[kH];
  red[t] = rl * wr_w[l*kH + t];
  __syncthreads();
  for (int o = 64; o > 0; o >>= 1){
    if (t < o) red[t] += red[t+o];
    __syncthreads();
  }
  float w = red[0] + wr_b[l];
  relterm[((size_t)l*kRels + r)*kH + t] = w * rl;
}

// ---------- CSR build over kN graph nodes (no global atomics) ----------

__global__ __launch_bounds__(256) void csr_hist_kernel(const int* __restrict__ dst,
    unsigned short* __restrict__ rank, unsigned int* __restrict__ hpart){
  __shared__ unsigned int hb[kHalf];
  int p = blockIdx.x;
  int base = blockIdx.y * kHalf;
  int t = threadIdx.x;
  for (int i = t; i < kHalf; i += 256) hb[i] = 0u;
  __syncthreads();
  for (int i = t; i < kChunk; i += 256){
    int e = p*kChunk + i;
    int d = dst[e];
    int rel = d - base;
    if ((unsigned)rel < (unsigned)kHalf){
      rank[e] = (unsigned short)atomicAdd(&hb[rel], 1u);
    }
  }
  __syncthreads();
  for (int i = t; i < kHalf; i += 256)
    hpart[(size_t)p*kN + base + i] = hb[i];
}

__global__ __launch_bounds__(256) void csr_col_kernel(unsigned int* __restrict__ hpart,
    int* __restrict__ deg){
  int bin = blockIdx.x*256 + threadIdx.x;
  if (bin >= kN) return;
  unsigned int s = 0;
#pragma unroll
  for (int p = 0; p < kNB; p++){
    size_t idx = (size_t)p*kN + bin;
    unsigned int v = hpart[idx];
    hpart[idx] = s;
    s += v;
  }
  deg[bin] = (int)s;
}

__global__ __launch_bounds__(256) void scanA_kernel(const int* __restrict__ deg,
    int* __restrict__ starts, int* __restrict__ bsum){
  __shared__ int buf[256];
  int gid = blockIdx.x*256 + threadIdx.x;
  int t = threadIdx.x;
  int v = (gid < kN) ? deg[gid] : 0;
  buf[t] = v;
  __syncthreads();
  for (int o = 1; o < 256; o <<= 1){
    int add = (t >= o) ? buf[t-o] : 0;
    __syncthreads();
    buf[t] += add;
    __syncthreads();
  }
  if (gid < kN) starts[gid] = buf[t] - v;
  if (t == 255) bsum[blockIdx.x] = buf[255];
}

__global__ __launch_bounds__(128) void scanB_kernel(const int* __restrict__ bsum,
    int* __restrict__ boffs, int nblk){
  __shared__ int buf[128];
  int t = threadIdx.x;
  int v = (t < nblk) ? bsum[t] : 0;
  buf[t] = v;
  __syncthreads();
  for (int o = 1; o < 128; o <<= 1){
    int add = (t >= o) ? buf[t-o] : 0;
    __syncthreads();
    buf[t] += add;
    __syncthreads();
  }
  if (t < nblk) boffs[t] = buf[t] - v;
}

__global__ __launch_bounds__(256) void scanC_kernel(int* __restrict__ starts,
    const int* __restrict__ boffs){
  int gid = blockIdx.x*256 + threadIdx.x;
  if (gid < kN) starts[gid] += boffs[blockIdx.x];
  if (gid == kN-1) starts[kN] = kE;
}

__global__ __launch_bounds__(256) void csr_place_kernel(const int* __restrict__ dst,
    const int* __restrict__ starts, const unsigned int* __restrict__ colOff,
    const unsigned short* __restrict__ rank, int* __restrict__ perm){
  int blk = blockIdx.x;                 // 128 blocks x 2000 edges
  int p = blk >> 2;                     // 4 blocks per sort chunk
  for (int i = threadIdx.x; i < 2000; i += 256){
    int e = blk*2000 + i;
    int d = dst[e];
    int pos = starts[d] + (int)colOff[(size_t)p*kN + d] + (int)rank[e];
    perm[pos] = e;
  }
}

__global__ void ub_kernel(const int* __restrict__ batch, int* __restrict__ ub){
  int j = threadIdx.x;
  if (j > kB) return;
  int lo = 0, hi = kN;
  while (lo < hi){
    int mid = (lo + hi) >> 1;
    if (batch[mid] < j) lo = mid + 1; else hi = mid;
  }
  ub[j] = lo;
}

// ---------- attention path ----------

// visit (640 x 4000 f32) -> visitbf (640 x 4096 bf16), pad cols zeroed
__global__ void cvt_visit_kernel(const float* __restrict__ visit, unsigned short* __restrict__ out){
  int i = blockIdx.x*256 + threadIdx.x;     // vec8 over 640*512
  if (i >= kBV*(kKPad/8)) return;
  int row = i >> 9;                          // / 512
  int col = (i & 511) * 8;
  unsigned short r[8];
  if (col < kNodes){
    const float* p = visit + (size_t)row*kNodes + col;
    const float4 a = *reinterpret_cast<const float4*>(p);
    const float4 b = *reinterpret_cast<const float4*>(p + 4);
    r[0]=f2bf(a.x); r[1]=f2bf(a.y); r[2]=f2bf(a.z); r[3]=f2bf(a.w);
    r[4]=f2bf(b.x); r[5]=f2bf(b.y); r[6]=f2bf(b.z); r[7]=f2bf(b.w);
  } else {
    for (int q = 0; q < 8; q++) r[q] = 0;
  }
  *reinterpret_cast<uint4*>(out + (size_t)row*kKPad + col) = *reinterpret_cast<uint4*>(r);
}

// all 3 layers of alpha_w (4000x4000 f32) -> (4096 x 4096 bf16), pads zeroed
__global__ void cvtW_kernel(const float* __restrict__ W, unsigned short* __restrict__ out){
  int i = blockIdx.x*256 + threadIdx.x;
  constexpr int perL = kMPad*(kKPad/8);
  if (i >= kL*perL) return;
  int l = i / perL;
  int rem = i - l*perL;
  int row = rem >> 9;
  int col = (rem & 511) * 8;
  unsigned short r[8];
  if (row < kNodes && col < kNodes){
    const float* p = W + (size_t)l*kNodes*kNodes + (size_t)row*kNodes + col;
    const float4 a = *reinterpret_cast<const float4*>(p);
    const float4 b = *reinterpret_cast<const float4*>(p + 4);
    r[0]=f2bf(a.x); r[1]=f2bf(a.y); r[2]=f2bf(a.z); r[3]=f2bf(a.w);
    r[4]=f2bf(b.x); r[5]=f2bf(b.y); r[6]=f2bf(b.z); r[7]=f2bf(b.w);
  } else {
    for (int q = 0; q < 8; q++) r[q] = 0;
  }
  *reinterpret_cast<uint4*>(out + (size_t)l*kMPad*kKPad + (size_t)row*kKPad + col)
      = *reinterpret_cast<uint4*>(r);
}

// S[l](640 x 4096) = A(640 x 4096) @ B_l(4096 x 4096)^T ; full K per block.
// BK=64; double-buffered LDS with prefetch-before-compute (depth-1 pipeline);
// global_load_lds source-pre-swizzle (slot ^= row&7) + swizzled ds_read;
// XCD-chunked bijective block swizzle, bm-fastest for B-panel L2 reuse.
__global__ __launch_bounds__(256) void gemm_bt_bf16(const unsigned short* __restrict__ A,
    const unsigned short* __restrict__ Ball, float* __restrict__ Sbase){
  __shared__ unsigned short As[2][128*64];
  __shared__ unsigned short Bs[2][128*64];
  // 480 blocks; 480 % 8 == 0 -> chunk=60 per XCD
  int wg = (blockIdx.x & 7)*60 + (blockIdx.x >> 3);
  int l = wg / 160;
  int rem = wg - l*160;
  int bn = rem / 5;
  int bm = rem - bn*5;
  const unsigned short* B = Ball + (size_t)l*kMPad*kKPad;
  float* C = Sbase + (size_t)l*kBV*kMPad;

  int t = threadIdx.x;
  int lane = t & 63, wave = t >> 6;
  int wm = (wave >> 1) * 64, wn = (wave & 1) * 64;
  int r = lane & 15, g = lane >> 4;

  // staging: wave stages rows [wave*32, wave*32+32) in 4 chunks of 8 rows.
  // lane: ri = lane>>3 (row in chunk), s = lane&7 (16B slot in 128B row).
  // LDS dest linear; global source k-slot pre-swizzled: slot' = s ^ ri.
  int ri = lane >> 3, s = lane & 7;
  int koff = ((s ^ ri) << 3);           // elements
  const unsigned short* Ag = A + (size_t)(bm*128 + wave*32 + ri)*kKPad + koff;
  const unsigned short* Bg = B + (size_t)(bn*128 + wave*32 + ri)*kKPad + koff;
  const size_t chunkStep = (size_t)8*kKPad;   // 8 rows

  auto STAGE = [&](int buf, int tstep){
    const unsigned short* a = Ag + tstep*64;
    const unsigned short* b = Bg + tstep*64;
#pragma unroll
    for (int c = 0; c < 4; c++){
      gload_lds16(a + c*chunkStep, &As[buf][(wave*32 + c*8)*64]);
      gload_lds16(b + c*chunkStep, &Bs[buf][(wave*32 + c*8)*64]);
    }
  };

  f32x4 acc[4][4];
#pragma unroll
  for (int i = 0; i < 4; i++)
#pragma unroll
    for (int j = 0; j < 4; j++) acc[i][j] = f32x4{0.f,0.f,0.f,0.f};

  constexpr int NT = kKPad / 64;        // 64 K-steps
  STAGE(0, 0);
  __syncthreads();                       // implicit vmcnt(0): tile 0 staged
  int cur = 0;
  for (int tstep = 0; tstep < NT; tstep++){
    if (tstep + 1 < NT) STAGE(cur ^ 1, tstep + 1);   // prefetch next tile (overlaps compute)
#pragma unroll
    for (int ksub = 0; ksub < 2; ksub++){
      bf16x8 af[4], bf[4];
#pragma unroll
      for (int i = 0; i < 4; i++){
        int arow = wm + i*16 + r;
        int brow = wn + i*16 + r;
        int slot = ((ksub << 2) + g);
        af[i] = *reinterpret_cast<const bf16x8*>(&As[cur][arow*64 + ((slot ^ (arow & 7)) << 3)]);
        bf[i] = *reinterpret_cast<const bf16x8*>(&Bs[cur][brow*64 + ((slot ^ (brow & 7)) << 3)]);
      }
#pragma unroll
      for (int i = 0; i < 4; i++)
#pragma unroll
        for (int j = 0; j < 4; j++)
          acc[i][j] = __builtin_amdgcn_mfma_f32_16x16x32_bf16(af[i], bf[j], acc[i][j], 0, 0, 0);
    }
    __syncthreads();   // implicit vmcnt(0)+lgkmcnt(0): prefetch landed, all reads of cur done
    cur ^= 1;
  }
#pragma unroll
  for (int i = 0; i < 4; i++)
#pragma unroll
    for (int j = 0; j < 4; j++){
      int row = bm*128 + wm + i*16 + g*4;
      int col = bn*128 + wn + j*16 + r;
#pragma unroll
      for (int q = 0; q < 4; q++)
        C[(size_t)(row + q)*kMPad + col] = acc[i][j][q];
    }
}

// beta[l][bv] = tanh(visit[bv]·beta_w[l] + beta_b[l]) * exp(0.03*(V - v)), all layers
__global__ __launch_bounds__(256) void beta_all_kernel(const float* __restrict__ visit,
    const float* __restrict__ beta_w, const float* __restrict__ beta_b,
    float* __restrict__ beta){
  int wid = (blockIdx.x*256 + threadIdx.x) >> 6;
  int lane = threadIdx.x & 63;
  if (wid >= kL*kBV) return;
  int l = wid / kBV, bv = wid - l*kBV;
  const float* row = visit + (size_t)bv*kNodes;
  const float* bw = beta_w + (size_t)l*kNodes;
  float s = 0.f;
  for (int k = lane; k < kNodes; k += 64) s = fmaf(row[k], bw[k], s);
#pragma unroll
  for (int o = 32; o > 0; o >>= 1) s += __shfl_down(s, o);
  if (lane == 0){
    int v = bv % kV;
    float lam = __expf(0.03f * (float)(kV - v));
    beta[wid] = tanhf(s + beta_b[l]) * lam;
  }
}

// attn[l][b][m] = sum_v softmax_v(S) * beta[l,b,v]  (all layers)
__global__ __launch_bounds__(256) void attn_kernel(const float* __restrict__ S,
    const float* __restrict__ beta, float* __restrict__ attn){
  int idx = blockIdx.x*256 + threadIdx.x;
  if (idx >= kL*kB*kNodes) return;
  int l = idx / (kB*kNodes);
  int rem = idx - l*(kB*kNodes);
  int b = rem / kNodes;
  int m = rem - b*kNodes;
  const float* S0 = S + (size_t)l*kBV*kMPad + (size_t)b*kV*kMPad + m;
  float vals[kV];
  float mx = -1e30f;
#pragma unroll
  for (int v = 0; v < kV; v++){
    float s = S0[(size_t)v*kMPad];
    vals[v] = s; mx = fmaxf(mx, s);
  }
  float se = 0.f, ws = 0.f;
  const float* bp = beta + l*kBV + b*kV;
#pragma unroll
  for (int v = 0; v < kV; v++){ float e = __expf(vals[v] - mx); se += e; ws = fmaf(e, bp[v], ws); }
  attn[idx] = ws / se;
}

// att_n[l][n] = attn[l][batch[n]][node_ids[n]] — collapse 2-deep random chain
__global__ void attn_gather_kernel(const int* __restrict__ batch,
    const int* __restrict__ node_ids, const float* __restrict__ attn,
    float* __restrict__ att_n){
  int idx = blockIdx.x*256 + threadIdx.x;
  if (idx >= kL*kN) return;
  int l = idx / kN, n = idx - l*kN;
  att_n[idx] = attn[(size_t)l*kB*kNodes + (size_t)batch[n]*kNodes + node_ids[n]];
}

// ---------- GNN layer ----------

// bf16 x-gather: 256B/row instead of 512B — halves the dominant gather traffic
__global__ __launch_bounds__(256) void agg_kernel(const int* __restrict__ starts,
    const int* __restrict__ perm, const int* __restrict__ src, const int* __restrict__ rel_ids,
    const float* __restrict__ att_n_l, const float* __restrict__ relterm_l,
    const unsigned short* __restrict__ xbf, float* __restrict__ agg){
  int wid = (blockIdx.x*256 + threadIdx.x) >> 6;
  int lane = threadIdx.x & 63;
  if (wid >= kN) return;
  int p0 = starts[wid], p1 = starts[wid+1];
  int c = lane*2;
  float a0 = 0.f, a1 = 0.f;
  for (int p = p0; p < p1; p++){
    int e = perm[p];
    int s = src[e];
    float at = att_n_l[s];
    unsigned int xv = *reinterpret_cast<const unsigned int*>(&xbf[(size_t)s*kH + c]);
    float2 rt = *reinterpret_cast<const float2*>(&relterm_l[(size_t)rel_ids[e]*kH + c]);
    float x0 = __uint_as_float(xv << 16);            // low bf16
    float x1 = __uint_as_float(xv & 0xFFFF0000u);    // high bf16
    float m0 = fmaf(x0, at, rt.x); m0 = m0 > 0.f ? m0 : 0.f;
    float m1 = fmaf(x1, at, rt.y); m1 = m1 > 0.f ? m1 : 0.f;
    a0 += m0; a1 += m1;
  }
  *reinterpret_cast<float2*>(&agg[(size_t)wid*kH + c]) = float2{a0, a1};
}

__global__ __launch_bounds__(256) void nn_kernel(const float* __restrict__ agg,
    float* __restrict__ x, unsigned short* __restrict__ xbf,
    const float* __restrict__ nn_wT_l, const float* __restrict__ nn_b_l){
  __shared__ float rows[8][kH];
  int rb = blockIdx.x * 8;
  int t = threadIdx.x;
#pragma unroll
  for (int i = 0; i < 4; i++){
    int idx = t + i*256;
    int rr = idx >> 7, cc = idx & (kH-1);
    size_t gi = (size_t)(rb + rr)*kH + cc;
    rows[rr][cc] = agg[gi] + x[gi];
  }
  __syncthreads();
  int cc = t & (kH-1);
  int r0 = (t >> 7) * 4;
  float acc0 = 0.f, acc1 = 0.f, acc2 = 0.f, acc3 = 0.f;
#pragma unroll 8
  for (int k = 0; k < kH; k++){
    float w = nn_wT_l[k*kH + cc];
    acc0 = fmaf(rows[r0+0][k], w, acc0);
    acc1 = fmaf(rows[r0+1][k], w, acc1);
    acc2 = fmaf(rows[r0+2][k], w, acc2);
    acc3 = fmaf(rows[r0+3][k], w, acc3);
  }
  float b = nn_b_l[cc];
  float o0 = fmaxf(acc0 + b, 0.f);
  float o1 = fmaxf(acc1 + b, 0.f);
  float o2 = fmaxf(acc2 + b, 0.f);
  float o3 = fmaxf(acc3 + b, 0.f);
  x[(size_t)(rb+r0+0)*kH + cc] = o0;  xbf[(size_t)(rb+r0+0)*kH + cc] = f2bf(o0);
  x[(size_t)(rb+r0+1)*kH + cc] = o1;  xbf[(size_t)(rb+r0+1)*kH + cc] = f2bf(o1);
  x[(size_t)(rb+r0+2)*kH + cc] = o2;  xbf[(size_t)(rb+r0+2)*kH + cc] = f2bf(o2);
  x[(size_t)(rb+r0+3)*kH + cc] = o3;  xbf[(size_t)(rb+r0+3)*kH + cc] = f2bf(o3);
}

// ---------- readout (fused; no atomics) ----------

__global__ __launch_bounds__(128) void pool_part_kernel(const float* __restrict__ x,
    const int* __restrict__ ub, float* __restrict__ pp){
  int s = blockIdx.x, b = blockIdx.y, c = threadIdx.x;
  int lo = ub[b], len = ub[b+1] - lo;
  int i0 = lo + (int)(((long long)len * s) >> 3);
  int i1 = lo + (int)(((long long)len * (s+1)) >> 3);
  float acc = 0.f;
  for (int i = i0; i < i1; i++) acc += x[(size_t)i*kH + c];
  pp[(size_t)(b*8 + s)*kH + c] = acc;
}

__global__ __launch_bounds__(128) void xnode1_kernel(const float* __restrict__ ehr,
    const float* __restrict__ node_emb, float* __restrict__ pn, float* __restrict__ ps){
  int s = blockIdx.x, b = blockIdx.y, c = threadIdx.x;
  int n0 = s * (kNodes/8), n1 = n0 + (kNodes/8);
  float acc = 0.f, es = 0.f;
  for (int n = n0; n < n1; n++){
    float e = ehr[(size_t)b*kNodes + n];
    es += e;
    acc = fmaf(e, node_emb[(size_t)n*kH + c], acc);
  }
  pn[(size_t)(b*8 + s)*kH + c] = acc;
  if (c == 0) ps[b*8 + s] = es;
}

// xg-finish + xnode-finish + final MLP in one kernel
__global__ __launch_bounds__(128) void readout_kernel(const float* __restrict__ pp,
    const int* __restrict__ ub, const float* __restrict__ pn, const float* __restrict__ ps,
    const float* __restrict__ lin_wT, const float* __restrict__ lin_b,
    const float* __restrict__ mlp_w, const float* __restrict__ mlp_b,
    float* __restrict__ out){
  int b = blockIdx.x, h = threadIdx.x;
  __shared__ float v[2*kH];
  __shared__ float ts[kH];
  float s = 0.f;
#pragma unroll
  for (int q = 0; q < 8; q++) s += pp[(size_t)(b*8 + q)*kH + h];
  int len = ub[b+1] - ub[b]; if (len < 1) len = 1;
  v[h] = s / (float)len;
  float acc = 0.f, es = 0.f;
#pragma unroll
  for (int q = 0; q < 8; q++){
    acc += pn[(size_t)(b*8 + q)*kH + h];
    es  += ps[b*8 + q];
  }
  ts[h] = acc / es;
  __syncthreads();
  float r = lin_b[h];
#pragma unroll 8
  for (int k = 0; k < kH; k++) r = fmaf(ts[k], lin_wT[k*kH + h], r);
  v[kH + h] = r;
  __syncthreads();
  float o = mlp_b[h];
#pragma unroll 8
  for (int k = 0; k < 2*kH; k++) o = fmaf(v[k], mlp_w[(size_t)h*2*kH + k], o);
  out[b*kH + h] = o;
}

} // namespace

extern "C" void kernel_launch(void* const* d_in, const int* in_sizes, int n_in,
                              void* d_out, int out_size, void* d_ws, size_t ws_size,
                              hipStream_t stream){
  const int*   node_ids = (const int*)d_in[0];
  const int*   rel_ids  = (const int*)d_in[1];
  const int*   e_src    = (const int*)d_in[2];
  const int*   e_dst    = e_src + kE;
  const int*   batch    = (const int*)d_in[3];
  const float* visit    = (const float*)d_in[4];
  const float* ehr      = (const float*)d_in[5];
  const float* node_emb = (const float*)d_in[6];
  const float* rel_emb  = (const float*)d_in[7];
  const float* lin_w    = (const float*)d_in[8];
  const float* lin_b    = (const float*)d_in[9];
  const float* alpha_w  = (const float*)d_in[10];
  const float* beta_w   = (const float*)d_in[12];
  const float* beta_b   = (const float*)d_in[13];
  const float* wr_w     = (const float*)d_in[14];
  const float* wr_b     = (const float*)d_in[15];
  const float* nn_w     = (const float*)d_in[16];
  const float* nn_b     = (const float*)d_in[17];
  const float* mlp_w    = (const float*)d_in[18];
  const float* mlp_b    = (const float*)d_in[19];
  float* out = (float*)d_out;

  char* w = (char*)d_ws;
  auto alloc = [&](size_t bytes)->char*{
    char* p = w; w += (bytes + 255) & ~(size_t)255; return p;
  };
  int*   starts = (int*)  alloc((size_t)(kN+1)*4);
  int*   deg    = (int*)  alloc((size_t)kN*4);
  int*   bsum   = (int*)  alloc(256*4);
  int*   boffs  = (int*)  alloc(256*4);
  int*   ub     = (int*)  alloc((kB+1)*4);
  int*   perm   = (int*)  alloc((size_t)kE*4);
  unsigned short* rank = (unsigned short*)alloc((size_t)kE*2);
  unsigned int* hpart  = (unsigned int*)alloc((size_t)kNB*kN*4);   // becomes colOff in place
  float* embLin = (float*)alloc((size_t)kNodes*kH*4);
  float* relLin = (float*)alloc((size_t)kRels*kH*4);
  float* relterm= (float*)alloc((size_t)kL*kRels*kH*4);
  float* linwT  = (float*)alloc((size_t)kH*kH*4);
  float* nnwT   = (float*)alloc((size_t)kL*kH*kH*4);
  float* x      = (float*)alloc((size_t)kN*kH*4);
  unsigned short* xbf = (unsigned short*)alloc((size_t)kN*kH*2);
  float* agg    = (float*)alloc((size_t)kN*kH*4);
  unsigned short* visitbf = (unsigned short*)alloc((size_t)kBV*kKPad*2);
  unsigned short* awbf    = (unsigned short*)alloc((size_t)kL*kMPad*kKPad*2);
  float* S      = (float*)alloc((size_t)kL*kBV*kMPad*4);
  float* attn   = (float*)alloc((size_t)kL*kB*kNodes*4);
  float* att_n  = (float*)alloc((size_t)kL*kN*4);
  float* beta   = (float*)alloc((size_t)kL*kBV*4);
  float* pp     = (float*)alloc((size_t)kB*8*kH*4);
  float* pn     = (float*)alloc((size_t)kB*8*kH*4);
  float* ps     = (float*)alloc((size_t)kB*8*4);
  if ((size_t)(w - (char*)d_ws) > ws_size) return;   // ws too small: fail visibly

  // prep
  transpose_kernel<<<4, 256, 0, stream>>>(lin_w, nn_w, linwT, nnwT);
  proj_kernel<<<kNodes + kRels, 128, 0, stream>>>(node_emb, rel_emb, linwT, lin_b, embLin, relLin);
  gather_x0_kernel<<<(kN*kH)/256, 256, 0, stream>>>(node_ids, embLin, x, xbf);
  relterm_kernel<<<kL*kRels, 128, 0, stream>>>(relLin, wr_w, wr_b, relterm);

  // CSR build (no global atomics)
  csr_hist_kernel<<<dim3(kNB, 2), 256, 0, stream>>>(e_dst, rank, hpart);
  csr_col_kernel<<<(kN+255)/256, 256, 0, stream>>>(hpart, deg);
  scanA_kernel<<<(kN+255)/256, 256, 0, stream>>>(deg, starts, bsum);
  scanB_kernel<<<1, 128, 0, stream>>>(bsum, boffs, (kN+255)/256);
  scanC_kernel<<<(kN+255)/256, 256, 0, stream>>>(starts, boffs);
  csr_place_kernel<<<128, 256, 0, stream>>>(e_dst, starts, hpart, rank, perm);
  ub_kernel<<<1, 64, 0, stream>>>(batch, ub);

  // attention path (all layers batched)
  cvt_visit_kernel<<<(kBV*(kKPad/8) + 255)/256, 256, 0, stream>>>(visit, visitbf);
  beta_all_kernel<<<kL*kBV/4, 256, 0, stream>>>(visit, beta_w, beta_b, beta);
  cvtW_kernel<<<(kL*kMPad*(kKPad/8) + 255)/256, 256, 0, stream>>>(alpha_w, awbf);
  gemm_bt_bf16<<<480, 256, 0, stream>>>(visitbf, awbf, S);
  attn_kernel<<<(kL*kB*kNodes + 255)/256, 256, 0, stream>>>(S, beta, attn);
  attn_gather_kernel<<<(kL*kN + 255)/256, 256, 0, stream>>>(batch, node_ids, attn, att_n);

  // GNN layers
  for (int l = 0; l < kL; l++){
    agg_kernel<<<kN/4, 256, 0, stream>>>(starts, perm, e_src, rel_ids,
        att_n + (size_t)l*kN, relterm + (size_t)l*kRels*kH, xbf, agg);
    nn_kernel<<<kN/8, 256, 0, stream>>>(agg, x, xbf, nnwT + (size_t)l*kH*kH, nn_b + (size_t)l*kH);
  }

  // readout
  pool_part_kernel<<<dim3(8, kB), 128, 0, stream>>>(x, ub, pp);
  xnode1_kernel<<<dim3(8, kB), 128, 0, stream>>>(ehr, node_emb, pn, ps);
  readout_kernel<<<kB, 128, 0, stream>>>(pp, ub, pn, ps, linwT, lin_b, mlp_w, mlp_b, out);
}

// Round 8
// 593.381 us; speedup vs baseline: 2.1044x; 1.0083x over previous
//
#include <hip/hip_runtime.h>

namespace {

constexpr int kNodes = 4000;        // node-TYPE vocabulary (attn/alpha space)
constexpr int kRels  = 400;
constexpr int kB     = 32;
constexpr int kV     = 20;
constexpr int kN     = 32000;       // graph nodes (CSR space)
constexpr int kE     = 256000;
constexpr int kH     = 128;
constexpr int kL     = 3;
constexpr int kMPad  = 4096;        // alpha_w m-dim padded (output tiling)
constexpr int kKW    = 4000;        // K kept exact: 125 x BK=32
constexpr int kBV    = kB * kV;     // 640
constexpr int kNB    = 32;          // CSR sort blocks
constexpr int kChunk = kE / kNB;    // 8000 edges per sort block
constexpr int kHalf  = 16000;       // bins per LDS pass (64KB LDS); 2*kHalf == kN

typedef __attribute__((ext_vector_type(8))) short bf16x8;
typedef __attribute__((ext_vector_type(4))) float f32x4;

__device__ inline unsigned short f2bf(float f){
  unsigned int u = __float_as_uint(f);
  u += 0x7FFFu + ((u >> 16) & 1u);      // round-to-nearest-even
  return (unsigned short)(u >> 16);
}

// global->LDS direct copy, 16B per lane, dest = wave-uniform base + lane*16
__device__ inline void gload_lds16(const unsigned short* g, unsigned short* l){
  __builtin_amdgcn_global_load_lds(
      (const __attribute__((address_space(1))) unsigned int*)(g),
      (__attribute__((address_space(3))) unsigned int*)(l),
      16, 0, 0);
}

// ---------- prep kernels ----------

__global__ void transpose_kernel(const float* __restrict__ lin_w, const float* __restrict__ nn_w,
                                 float* __restrict__ lin_wT, float* __restrict__ nn_wT){
  int m = blockIdx.x;
  const float* in = (m == 0) ? lin_w : nn_w + (size_t)(m-1)*kH*kH;
  float* out      = (m == 0) ? lin_wT : nn_wT + (size_t)(m-1)*kH*kH;
  for (int i = threadIdx.x; i < kH*kH; i += blockDim.x){
    int r = i >> 7, c = i & (kH-1);
    out[c*kH + r] = in[i];
  }
}

__global__ __launch_bounds__(128) void proj_kernel(const float* __restrict__ node_emb,
    const float* __restrict__ rel_emb, const float* __restrict__ lin_wT,
    const float* __restrict__ lin_b, float* __restrict__ emb_lin, float* __restrict__ rel_lin){
  int row = blockIdx.x;
  const float* src; float* dst;
  if (row < kNodes){ src = node_emb + (size_t)row*kH; dst = emb_lin + (size_t)row*kH; }
  else             { src = rel_emb + (size_t)(row-kNodes)*kH; dst = rel_lin + (size_t)(row-kNodes)*kH; }
  __shared__ float rs[kH];
  int h = threadIdx.x;
  rs[h] = src[h];
  __syncthreads();
  float acc = lin_b[h];
#pragma unroll 8
  for (int k = 0; k < kH; k++) acc = fmaf(rs[k], lin_wT[k*kH + h], acc);
  dst[h] = acc;
}

__global__ void gather_x0_kernel(const int* __restrict__ node_ids,
                                 const float* __restrict__ emb_lin, float* __restrict__ x,
                                 unsigned short* __restrict__ xbf){
  int idx = blockIdx.x*256 + threadIdx.x;
  if (idx < kN*kH){
    int i = idx >> 7, c = idx & (kH-1);
    float v = emb_lin[(size_t)node_ids[i]*kH + c];
    x[idx] = v;
    xbf[idx] = f2bf(v);
  }
}

__global__ __launch_bounds__(128) void relterm_kernel(const float* __restrict__ rel_lin,
    const float* __restrict__ wr_w, const float* __restrict__ wr_b, float* __restrict__ relterm){
  int l = blockIdx.x / kRels, r = blockIdx.x % kRels;
  int t = threadIdx.x;
  float rl = rel_lin[(size_t)r*kH + t];
  __shared__ float red[kH];
  red[t] = rl * wr_w[l*kH + t];
  __syncthreads();
  for (int o = 64; o > 0; o >>= 1){
    if (t < o) red[t] += red[t+o];
    __syncthreads();
  }
  float w = red[0] + wr_b[l];
  relterm[((size_t)l*kRels + r)*kH + t] = w * rl;
}

// ---------- CSR build over kN graph nodes (no global atomics) ----------

__global__ __launch_bounds__(256) void csr_hist_kernel(const int* __restrict__ dst,
    unsigned short* __restrict__ rank, unsigned int* __restrict__ hpart){
  __shared__ unsigned int hb[kHalf];
  int p = blockIdx.x;
  int base = blockIdx.y * kHalf;
  int t = threadIdx.x;
  for (int i = t; i < kHalf; i += 256) hb[i] = 0u;
  __syncthreads();
  for (int i = t; i < kChunk; i += 256){
    int e = p*kChunk + i;
    int d = dst[e];
    int rel = d - base;
    if ((unsigned)rel < (unsigned)kHalf){
      rank[e] = (unsigned short)atomicAdd(&hb[rel], 1u);
    }
  }
  __syncthreads();
  for (int i = t; i < kHalf; i += 256)
    hpart[(size_t)p*kN + base + i] = hb[i];
}

__global__ __launch_bounds__(256) void csr_col_kernel(unsigned int* __restrict__ hpart,
    int* __restrict__ deg){
  int bin = blockIdx.x*256 + threadIdx.x;
  if (bin >= kN) return;
  unsigned int s = 0;
#pragma unroll
  for (int p = 0; p < kNB; p++){
    size_t idx = (size_t)p*kN + bin;
    unsigned int v = hpart[idx];
    hpart[idx] = s;
    s += v;
  }
  deg[bin] = (int)s;
}

__global__ __launch_bounds__(256) void scanA_kernel(const int* __restrict__ deg,
    int* __restrict__ starts, int* __restrict__ bsum){
  __shared__ int buf[256];
  int gid = blockIdx.x*256 + threadIdx.x;
  int t = threadIdx.x;
  int v = (gid < kN) ? deg[gid] : 0;
  buf[t] = v;
  __syncthreads();
  for (int o = 1; o < 256; o <<= 1){
    int add = (t >= o) ? buf[t-o] : 0;
    __syncthreads();
    buf[t] += add;
    __syncthreads();
  }
  if (gid < kN) starts[gid] = buf[t] - v;
  if (t == 255) bsum[blockIdx.x] = buf[255];
}

__global__ __launch_bounds__(128) void scanB_kernel(const int* __restrict__ bsum,
    int* __restrict__ boffs, int nblk){
  __shared__ int buf[128];
  int t = threadIdx.x;
  int v = (t < nblk) ? bsum[t] : 0;
  buf[t] = v;
  __syncthreads();
  for (int o = 1; o < 128; o <<= 1){
    int add = (t >= o) ? buf[t-o] : 0;
    __syncthreads();
    buf[t] += add;
    __syncthreads();
  }
  if (t < nblk) boffs[t] = buf[t] - v;
}

__global__ __launch_bounds__(256) void scanC_kernel(int* __restrict__ starts,
    const int* __restrict__ boffs){
  int gid = blockIdx.x*256 + threadIdx.x;
  if (gid < kN) starts[gid] += boffs[blockIdx.x];
  if (gid == kN-1) starts[kN] = kE;
}

// writes src/rel per edge directly in CSR order (drops one indirection in aggnn)
__global__ __launch_bounds__(256) void csr_place_kernel(const int* __restrict__ dst,
    const int* __restrict__ src, const int* __restrict__ rel_ids,
    const int* __restrict__ starts, const unsigned int* __restrict__ colOff,
    const unsigned short* __restrict__ rank,
    int* __restrict__ src_perm, int* __restrict__ rel_perm){
  int blk = blockIdx.x;                 // 128 blocks x 2000 edges
  int p = blk >> 2;                     // 4 blocks per sort chunk
  for (int i = threadIdx.x; i < 2000; i += 256){
    int e = blk*2000 + i;
    int d = dst[e];
    int pos = starts[d] + (int)colOff[(size_t)p*kN + d] + (int)rank[e];
    src_perm[pos] = src[e];
    rel_perm[pos] = rel_ids[e];
  }
}

__global__ void ub_kernel(const int* __restrict__ batch, int* __restrict__ ub){
  int j = threadIdx.x;
  if (j > kB) return;
  int lo = 0, hi = kN;
  while (lo < hi){
    int mid = (lo + hi) >> 1;
    if (batch[mid] < j) lo = mid + 1; else hi = mid;
  }
  ub[j] = lo;
}

// ---------- attention path ----------

// visit (640 x 4000 f32) -> visitbf (640 x 4000 bf16)
__global__ void cvt_visit_kernel(const float* __restrict__ visit, unsigned short* __restrict__ out){
  int i = blockIdx.x*256 + threadIdx.x;     // vec8 over 640*500
  if (i >= kBV*(kKW/8)) return;
  int row = i / (kKW/8);
  int col = (i - row*(kKW/8)) * 8;
  const float* p = visit + (size_t)row*kKW + col;
  const float4 a = *reinterpret_cast<const float4*>(p);
  const float4 b = *reinterpret_cast<const float4*>(p + 4);
  unsigned short r[8] = {f2bf(a.x),f2bf(a.y),f2bf(a.z),f2bf(a.w),
                         f2bf(b.x),f2bf(b.y),f2bf(b.z),f2bf(b.w)};
  *reinterpret_cast<uint4*>(out + (size_t)row*kKW + col) = *reinterpret_cast<uint4*>(r);
}

// all 3 layers of alpha_w (4000x4000 f32) -> (4096 x 4000 bf16), pad rows zeroed
__global__ void cvtW_kernel(const float* __restrict__ W, unsigned short* __restrict__ out){
  int i = blockIdx.x*256 + threadIdx.x;
  constexpr int perL = kMPad*(kKW/8);
  if (i >= kL*perL) return;
  int l = i / perL;
  int rem = i - l*perL;
  int row = rem / (kKW/8);
  int col = (rem - row*(kKW/8)) * 8;
  unsigned short r[8];
  if (row < kNodes){
    const float* p = W + (size_t)l*kNodes*kNodes + (size_t)row*kKW + col;
    const float4 a = *reinterpret_cast<const float4*>(p);
    const float4 b = *reinterpret_cast<const float4*>(p + 4);
    r[0]=f2bf(a.x); r[1]=f2bf(a.y); r[2]=f2bf(a.z); r[3]=f2bf(a.w);
    r[4]=f2bf(b.x); r[5]=f2bf(b.y); r[6]=f2bf(b.z); r[7]=f2bf(b.w);
  } else {
    for (int q = 0; q < 8; q++) r[q] = 0;
  }
  *reinterpret_cast<uint4*>(out + (size_t)l*kMPad*kKW + (size_t)row*kKW + col)
      = *reinterpret_cast<uint4*>(r);
}

// S[lz](640 x 4096) = A(640 x Kslice) @ B_l(4096 x Kslice)^T ; lz = l*2+z
// BK=32, double-buffered LDS (32KB total -> 5 blocks/CU), depth-1 prefetch.
// 0-conflict both-sides swizzle: slot ^= (row>>1)&3 at 64B rows.
// XCD-chunked bijective block swizzle, bm-fastest for B-panel L2 reuse.
__global__ __launch_bounds__(256) void gemm_bt_bf16(const unsigned short* __restrict__ A,
    const unsigned short* __restrict__ Ball, float* __restrict__ Sbase){
  __shared__ unsigned short As[2][128*32];
  __shared__ unsigned short Bs[2][128*32];
  // 960 blocks; chunk = 120 per XCD
  int wg = (blockIdx.x & 7)*120 + (blockIdx.x >> 3);
  int lz = wg / 160;
  int rem = wg - lz*160;
  int bn = rem / 5;
  int bm = rem - bn*5;
  int l = lz >> 1, z = lz & 1;
  const unsigned short* B = Ball + (size_t)l*kMPad*kKW;
  float* C = Sbase + (size_t)lz*kBV*kMPad;
  int tile0 = z ? 63 : 0;               // 125 tiles total: 63 + 62
  int nt    = z ? 62 : 63;

  int t = threadIdx.x;
  int lane = t & 63, wave = t >> 6;
  int wm = (wave >> 1) * 64, wn = (wave & 1) * 64;
  int r = lane & 15, g = lane >> 4;

  // staging: wave stages rows [wave*32, wave*32+32) in 2 chunks of 16 rows.
  // lane: ri = lane>>2 (row in 16-chunk), s = lane&3 (16B slot in 64B row).
  // LDS dest linear; global source k-slot pre-swizzled: slot' = s ^ ((ri>>1)&3).
  int ri = lane >> 2, s = lane & 3;
  int koff = ((s ^ ((ri >> 1) & 3)) << 3);   // elements
  const unsigned short* Ag = A + (size_t)(bm*128 + wave*32 + ri)*kKW + tile0*32 + koff;
  const unsigned short* Bg = B + (size_t)(bn*128 + wave*32 + ri)*kKW + tile0*32 + koff;
  const size_t rstep = (size_t)16*kKW;       // 16 rows

  f32x4 acc[4][4];
#pragma unroll
  for (int i = 0; i < 4; i++)
#pragma unroll
    for (int j = 0; j < 4; j++) acc[i][j] = f32x4{0.f,0.f,0.f,0.f};

  auto STAGE = [&](int buf, int ts){
    const unsigned short* a = Ag + ts*32;
    const unsigned short* b = Bg + ts*32;
    gload_lds16(a,         &As[buf][(wave*32     )*32]);
    gload_lds16(a + rstep, &As[buf][(wave*32 + 16)*32]);
    gload_lds16(b,         &Bs[buf][(wave*32     )*32]);
    gload_lds16(b + rstep, &Bs[buf][(wave*32 + 16)*32]);
  };

  STAGE(0, 0);
  for (int ts = 0; ts < nt; ts++){
    int cur = ts & 1;
    __syncthreads();                   // drains vmcnt: STAGE(ts) landed for all waves
    if (ts + 1 < nt) STAGE(cur ^ 1, ts + 1);   // prefetch overlaps this tile's compute
    bf16x8 af[4], bf[4];
#pragma unroll
    for (int i = 0; i < 4; i++){
      int arow = wm + i*16 + r;
      int brow = wn + i*16 + r;
      af[i] = *reinterpret_cast<const bf16x8*>(
          &As[cur][arow*32 + ((g ^ ((arow >> 1) & 3)) << 3)]);
      bf[i] = *reinterpret_cast<const bf16x8*>(
          &Bs[cur][brow*32 + ((g ^ ((brow >> 1) & 3)) << 3)]);
    }
#pragma unroll
    for (int i = 0; i < 4; i++)
#pragma unroll
      for (int j = 0; j < 4; j++)
        acc[i][j] = __builtin_amdgcn_mfma_f32_16x16x32_bf16(af[i], bf[j], acc[i][j], 0, 0, 0);
  }
#pragma unroll
  for (int i = 0; i < 4; i++)
#pragma unroll
    for (int j = 0; j < 4; j++){
      int row = bm*128 + wm + i*16 + g*4;
      int col = bn*128 + wn + j*16 + r;
#pragma unroll
      for (int q = 0; q < 4; q++)
        C[(size_t)(row + q)*kMPad + col] = acc[i][j][q];
    }
}

// beta[l][bv] = tanh(visit[bv]·beta_w[l] + beta_b[l]) * exp(0.03*(V - v)), all layers
__global__ __launch_bounds__(256) void beta_all_kernel(const float* __restrict__ visit,
    const float* __restrict__ beta_w, const float* __restrict__ beta_b,
    float* __restrict__ beta){
  int wid = (blockIdx.x*256 + threadIdx.x) >> 6;
  int lane = threadIdx.x & 63;
  if (wid >= kL*kBV) return;
  int l = wid / kBV, bv = wid - l*kBV;
  const float* row = visit + (size_t)bv*kNodes;
  const float* bw = beta_w + (size_t)l*kNodes;
  float s = 0.f;
  for (int k = lane; k < kNodes; k += 64) s = fmaf(row[k], bw[k], s);
#pragma unroll
  for (int o = 32; o > 0; o >>= 1) s += __shfl_down(s, o);
  if (lane == 0){
    int v = bv % kV;
    float lam = __expf(0.03f * (float)(kV - v));
    beta[wid] = tanhf(s + beta_b[l]) * lam;
  }
}

// attn[l][b][m] = sum_v softmax_v(S0+S1) * beta[l,b,v]  (all layers)
__global__ __launch_bounds__(256) void attn_kernel(const float* __restrict__ S,
    const float* __restrict__ beta, float* __restrict__ attn){
  int idx = blockIdx.x*256 + threadIdx.x;
  if (idx >= kL*kB*kNodes) return;
  int l = idx / (kB*kNodes);
  int rem = idx - l*(kB*kNodes);
  int b = rem / kNodes;
  int m = rem - b*kNodes;
  const float* S0 = S + (size_t)(l*2)*kBV*kMPad + (size_t)b*kV*kMPad + m;
  const float* S1 = S0 + (size_t)kBV*kMPad;
  float vals[kV];
  float mx = -1e30f;
#pragma unroll
  for (int v = 0; v < kV; v++){
    float s = S0[(size_t)v*kMPad] + S1[(size_t)v*kMPad];
    vals[v] = s; mx = fmaxf(mx, s);
  }
  float se = 0.f, ws = 0.f;
  const float* bp = beta + l*kBV + b*kV;
#pragma unroll
  for (int v = 0; v < kV; v++){ float e = __expf(vals[v] - mx); se += e; ws = fmaf(e, bp[v], ws); }
  attn[idx] = ws / se;
}

// att_e[l][p] = attn[l][batch[s]][node_ids[s]], s = src_perm[p] (perm-ordered, all layers)
__global__ void att_e_kernel(const int* __restrict__ src_perm, const int* __restrict__ batch,
    const int* __restrict__ node_ids, const float* __restrict__ attn,
    float* __restrict__ att_e){
  int idx = blockIdx.x*256 + threadIdx.x;
  if (idx >= kL*kE) return;
  int l = idx / kE, p = idx - l*kE;
  int s = src_perm[p];
  att_e[idx] = attn[(size_t)l*kB*kNodes + (size_t)batch[s]*kNodes + node_ids[s]];
}

// ---------- GNN layer: fused aggregate + nn (512 threads = 8 waves, 8 nodes/block) ----------

__global__ __launch_bounds__(512) void aggnn_kernel(const int* __restrict__ starts,
    const int* __restrict__ src_perm, const int* __restrict__ rel_perm,
    const float* __restrict__ att_e_l, const float* __restrict__ relterm_l,
    const unsigned short* __restrict__ xbf_in, unsigned short* __restrict__ xbf_out,
    float* __restrict__ x, const float* __restrict__ nn_wT_l, const float* __restrict__ nn_b_l){
  __shared__ float rows[8][kH];
  int t = threadIdx.x;
  int wv = t >> 6, lane = t & 63;
  int node = blockIdx.x*8 + wv;
  int p0 = starts[node], p1 = starts[node+1];
  int c = lane*2;
  float a0 = 0.f, a1 = 0.f;
  for (int p = p0; p < p1; p++){
    float at = att_e_l[p];
    int s = src_perm[p];
    int rel = rel_perm[p];
    unsigned int xv = *reinterpret_cast<const unsigned int*>(&xbf_in[(size_t)s*kH + c]);
    float2 rt = *reinterpret_cast<const float2*>(&relterm_l[(size_t)rel*kH + c]);
    float x0 = __uint_as_float(xv << 16);            // low bf16
    float x1 = __uint_as_float(xv & 0xFFFF0000u);    // high bf16
    float m0 = fmaf(x0, at, rt.x); m0 = m0 > 0.f ? m0 : 0.f;
    float m1 = fmaf(x1, at, rt.y); m1 = m1 > 0.f ? m1 : 0.f;
    a0 += m0; a1 += m1;
  }
  size_t gi = (size_t)node*kH + c;
  rows[wv][c]   = a0 + x[gi];
  rows[wv][c+1] = a1 + x[gi+1];
  __syncthreads();
  int cc = t & 127;
  int r0 = (t >> 7) * 2;                 // rows {0,1},{2,3},{4,5},{6,7}
  float acc0 = 0.f, acc1 = 0.f;
#pragma unroll 8
  for (int k = 0; k < kH; k++){
    float w = nn_wT_l[k*kH + cc];
    acc0 = fmaf(rows[r0  ][k], w, acc0);
    acc1 = fmaf(rows[r0+1][k], w, acc1);
  }
  float b = nn_b_l[cc];
  float o0 = fmaxf(acc0 + b, 0.f);
  float o1 = fmaxf(acc1 + b, 0.f);
  size_t n0 = (size_t)(blockIdx.x*8 + r0)*kH + cc;
  x[n0]        = o0;  xbf_out[n0]        = f2bf(o0);
  x[n0 + kH]   = o1;  xbf_out[n0 + kH]   = f2bf(o1);
}

// ---------- readout (fused; no atomics) ----------

__global__ __launch_bounds__(128) void pool_part_kernel(const float* __restrict__ x,
    const int* __restrict__ ub, float* __restrict__ pp){
  int s = blockIdx.x, b = blockIdx.y, c = threadIdx.x;
  int lo = ub[b], len = ub[b+1] - lo;
  int i0 = lo + (int)(((long long)len * s) >> 3);
  int i1 = lo + (int)(((long long)len * (s+1)) >> 3);
  float acc = 0.f;
  for (int i = i0; i < i1; i++) acc += x[(size_t)i*kH + c];
  pp[(size_t)(b*8 + s)*kH + c] = acc;
}

__global__ __launch_bounds__(128) void xnode1_kernel(const float* __restrict__ ehr,
    const float* __restrict__ node_emb, float* __restrict__ pn, float* __restrict__ ps){
  int s = blockIdx.x, b = blockIdx.y, c = threadIdx.x;
  int n0 = s * (kNodes/8), n1 = n0 + (kNodes/8);
  float acc = 0.f, es = 0.f;
  for (int n = n0; n < n1; n++){
    float e = ehr[(size_t)b*kNodes + n];
    es += e;
    acc = fmaf(e, node_emb[(size_t)n*kH + c], acc);
  }
  pn[(size_t)(b*8 + s)*kH + c] = acc;
  if (c == 0) ps[b*8 + s] = es;
}

// xg-finish + xnode-finish + final MLP in one kernel
__global__ __launch_bounds__(128) void readout_kernel(const float* __restrict__ pp,
    const int* __restrict__ ub, const float* __restrict__ pn, const float* __restrict__ ps,
    const float* __restrict__ lin_wT, const float* __restrict__ lin_b,
    const float* __restrict__ mlp_w, const float* __restrict__ mlp_b,
    float* __restrict__ out){
  int b = blockIdx.x, h = threadIdx.x;
  __shared__ float v[2*kH];
  __shared__ float ts[kH];
  float s = 0.f;
#pragma unroll
  for (int q = 0; q < 8; q++) s += pp[(size_t)(b*8 + q)*kH + h];
  int len = ub[b+1] - ub[b]; if (len < 1) len = 1;
  v[h] = s / (float)len;
  float acc = 0.f, es = 0.f;
#pragma unroll
  for (int q = 0; q < 8; q++){
    acc += pn[(size_t)(b*8 + q)*kH + h];
    es  += ps[b*8 + q];
  }
  ts[h] = acc / es;
  __syncthreads();
  float r = lin_b[h];
#pragma unroll 8
  for (int k = 0; k < kH; k++) r = fmaf(ts[k], lin_wT[k*kH + h], r);
  v[kH + h] = r;
  __syncthreads();
  float o = mlp_b[h];
#pragma unroll 8
  for (int k = 0; k < 2*kH; k++) o = fmaf(v[k], mlp_w[(size_t)h*2*kH + k], o);
  out[b*kH + h] = o;
}

} // namespace

extern "C" void kernel_launch(void* const* d_in, const int* in_sizes, int n_in,
                              void* d_out, int out_size, void* d_ws, size_t ws_size,
                              hipStream_t stream){
  const int*   node_ids = (const int*)d_in[0];
  const int*   rel_ids  = (const int*)d_in[1];
  const int*   e_src    = (const int*)d_in[2];
  const int*   e_dst    = e_src + kE;
  const int*   batch    = (const int*)d_in[3];
  const float* visit    = (const float*)d_in[4];
  const float* ehr      = (const float*)d_in[5];
  const float* node_emb = (const float*)d_in[6];
  const float* rel_emb  = (const float*)d_in[7];
  const float* lin_w    = (const float*)d_in[8];
  const float* lin_b    = (const float*)d_in[9];
  const float* alpha_w  = (const float*)d_in[10];
  const float* beta_w   = (const float*)d_in[12];
  const float* beta_b   = (const float*)d_in[13];
  const float* wr_w     = (const float*)d_in[14];
  const float* wr_b     = (const float*)d_in[15];
  const float* nn_w     = (const float*)d_in[16];
  const float* nn_b     = (const float*)d_in[17];
  const float* mlp_w    = (const float*)d_in[18];
  const float* mlp_b    = (const float*)d_in[19];
  float* out = (float*)d_out;

  char* w = (char*)d_ws;
  auto alloc = [&](size_t bytes)->char*{
    char* p = w; w += (bytes + 255) & ~(size_t)255; return p;
  };
  int*   starts = (int*)  alloc((size_t)(kN+1)*4);
  int*   deg    = (int*)  alloc((size_t)kN*4);
  int*   bsum   = (int*)  alloc(256*4);
  int*   boffs  = (int*)  alloc(256*4);
  int*   ub     = (int*)  alloc((kB+1)*4);
  int*   src_perm = (int*)alloc((size_t)kE*4);
  int*   rel_perm = (int*)alloc((size_t)kE*4);
  unsigned short* rank = (unsigned short*)alloc((size_t)kE*2);
  unsigned int* hpart  = (unsigned int*)alloc((size_t)kNB*kN*4);   // becomes colOff in place
  float* embLin = (float*)alloc((size_t)kNodes*kH*4);
  float* relLin = (float*)alloc((size_t)kRels*kH*4);
  float* relterm= (float*)alloc((size_t)kL*kRels*kH*4);
  float* linwT  = (float*)alloc((size_t)kH*kH*4);
  float* nnwT   = (float*)alloc((size_t)kL*kH*kH*4);
  float* x      = (float*)alloc((size_t)kN*kH*4);
  unsigned short* xbfA = (unsigned short*)alloc((size_t)kN*kH*2);
  unsigned short* xbfB = (unsigned short*)alloc((size_t)kN*kH*2);
  unsigned short* visitbf = (unsigned short*)alloc((size_t)kBV*kKW*2);
  unsigned short* awbf    = (unsigned short*)alloc((size_t)kL*kMPad*kKW*2);
  float* S      = (float*)alloc((size_t)kL*2*kBV*kMPad*4);
  float* attn   = (float*)alloc((size_t)kL*kB*kNodes*4);
  float* att_e  = (float*)alloc((size_t)kL*kE*4);
  float* beta   = (float*)alloc((size_t)kL*kBV*4);
  float* pp     = (float*)alloc((size_t)kB*8*kH*4);
  float* pn     = (float*)alloc((size_t)kB*8*kH*4);
  float* ps     = (float*)alloc((size_t)kB*8*4);
  if ((size_t)(w - (char*)d_ws) > ws_size) return;   // ws too small: fail visibly

  // prep
  transpose_kernel<<<4, 256, 0, stream>>>(lin_w, nn_w, linwT, nnwT);
  proj_kernel<<<kNodes + kRels, 128, 0, stream>>>(node_emb, rel_emb, linwT, lin_b, embLin, relLin);
  gather_x0_kernel<<<(kN*kH)/256, 256, 0, stream>>>(node_ids, embLin, x, xbfA);
  relterm_kernel<<<kL*kRels, 128, 0, stream>>>(relLin, wr_w, wr_b, relterm);

  // CSR build (no global atomics)
  csr_hist_kernel<<<dim3(kNB, 2), 256, 0, stream>>>(e_dst, rank, hpart);
  csr_col_kernel<<<(kN+255)/256, 256, 0, stream>>>(hpart, deg);
  scanA_kernel<<<(kN+255)/256, 256, 0, stream>>>(deg, starts, bsum);
  scanB_kernel<<<1, 128, 0, stream>>>(bsum, boffs, (kN+255)/256);
  scanC_kernel<<<(kN+255)/256, 256, 0, stream>>>(starts, boffs);
  csr_place_kernel<<<128, 256, 0, stream>>>(e_dst, e_src, rel_ids, starts, hpart, rank,
                                            src_perm, rel_perm);
  ub_kernel<<<1, 64, 0, stream>>>(batch, ub);

  // attention path (all layers batched)
  cvt_visit_kernel<<<(kBV*(kKW/8) + 255)/256, 256, 0, stream>>>(visit, visitbf);
  beta_all_kernel<<<kL*kBV/4, 256, 0, stream>>>(visit, beta_w, beta_b, beta);
  cvtW_kernel<<<(kL*kMPad*(kKW/8) + 255)/256, 256, 0, stream>>>(alpha_w, awbf);
  gemm_bt_bf16<<<960, 256, 0, stream>>>(visitbf, awbf, S);
  attn_kernel<<<(kL*kB*kNodes + 255)/256, 256, 0, stream>>>(S, beta, attn);
  att_e_kernel<<<(kL*kE + 255)/256, 256, 0, stream>>>(src_perm, batch, node_ids, attn, att_e);

  // GNN layers (fused aggregate+nn; xbf ping-pong, x f32 block-local in-place)
  unsigned short* xin = xbfA;
  unsigned short* xout = xbfB;
  for (int l = 0; l < kL; l++){
    aggnn_kernel<<<kN/8, 512, 0, stream>>>(starts, src_perm, rel_perm,
        att_e + (size_t)l*kE, relterm + (size_t)l*kRels*kH,
        xin, xout, x, nnwT + (size_t)l*kH*kH, nn_b + (size_t)l*kH);
    unsigned short* tmp = xin; xin = xout; xout = tmp;
  }

  // readout
  pool_part_kernel<<<dim3(8, kB), 128, 0, stream>>>(x, ub, pp);
  xnode1_kernel<<<dim3(8, kB), 128, 0, stream>>>(ehr, node_emb, pn, ps);
  readout_kernel<<<kB, 128, 0, stream>>>(pp, ub, pn, ps, linwT, lin_b, mlp_w, mlp_b, out);
}